// Round 3
// baseline (1921.753 us; speedup 1.0000x reference)
//
#include <hip/hip_runtime.h>
#include <hip/hip_bf16.h>

typedef __hip_bfloat16 bf16;
#define SLOPE 0.2f

__device__ __forceinline__ float b2f(bf16 v) { return __bfloat162float(v); }

union BU4 { uint2 u; bf16 b[4]; };

// ---------------- dtype detect: flag=0 -> buffers are bf16, flag=1 -> fp32 ----------------
// Reads low 16 bits of first 256 element-pairs of x. If x is bf16, those are real
// N(0,1) bf16 values (|v| in ~(1e-6,100)). If x is fp32, they are mantissa garbage
// (~10% land in that range). Majority vote.
__global__ void k_detect(const void* __restrict__ x, int* __restrict__ flag) {
    const unsigned short* u = (const unsigned short*)x;
    int tid = threadIdx.x;
    int nice = 0;
    for (int i = tid; i < 256; i += 64) {
        unsigned int bits = ((unsigned int)u[2 * i]) << 16;
        float v = __uint_as_float(bits);
        float av = fabsf(v);
        if (v == 0.0f || (av > 1e-6f && av < 100.0f)) ++nice;
    }
    for (int off = 32; off > 0; off >>= 1) nice += __shfl_down(nice, off, 64);
    if (tid == 0) *flag = (nice >= 192) ? 0 : 1;
}

__global__ void k_convert(const void* __restrict__ src, bf16* __restrict__ dst, int n,
                          const int* __restrict__ flag) {
    int i = blockIdx.x * blockDim.x + threadIdx.x;
    if (i >= n) return;
    if (*flag) dst[i] = __float2bfloat16(((const float*)src)[i]);
    else       dst[i] = ((const bf16*)src)[i];
}

// ---------------- CSR build ----------------
__global__ void k_hist(const int* __restrict__ dst, int* __restrict__ cnt, int E) {
    int e = blockIdx.x * blockDim.x + threadIdx.x;
    if (e < E) atomicAdd(&cnt[dst[e]], 1);
}

__global__ void k_scan(const int* __restrict__ cnt, int* __restrict__ rowptr, int n) {
    __shared__ int sh[1024];
    int tid = threadIdx.x;
    int chunk = (n + 1023) >> 10;
    int start = tid * chunk;
    int end = min(start + chunk, n);
    int s = 0;
    for (int i = start; i < end; ++i) s += cnt[i];
    sh[tid] = s;
    __syncthreads();
    for (int off = 1; off < 1024; off <<= 1) {
        int v = (tid >= off) ? sh[tid - off] : 0;
        __syncthreads();
        sh[tid] += v;
        __syncthreads();
    }
    int base = (tid > 0) ? sh[tid - 1] : 0;
    for (int i = start; i < end; ++i) { rowptr[i] = base; base += cnt[i]; }
    if (tid == 1023) rowptr[n] = sh[1023];
}

__global__ void k_copy_i(const int* __restrict__ a, int* __restrict__ b, int n) {
    int i = blockIdx.x * blockDim.x + threadIdx.x;
    if (i < n) b[i] = a[i];
}

__global__ void k_scatter(const int* __restrict__ src, const int* __restrict__ dst,
                          int* __restrict__ cursor, int* __restrict__ csr_src,
                          int* __restrict__ csr_dst, int E) {
    int e = blockIdx.x * blockDim.x + threadIdx.x;
    if (e < E) {
        int d = dst[e];
        int p = atomicAdd(&cursor[d], 1);
        csr_src[p] = src[e];
        csr_dst[p] = d;
    }
}

// ---------------- GEMM (adaptive A dtype): C[N,M](bf16) = A[N,K] @ W[K,M](bf16) ----------------
__global__ void k_gemm_adapt(const void* __restrict__ Araw, const bf16* __restrict__ W,
                             bf16* __restrict__ C, int Nrows, int K, int M,
                             const int* __restrict__ flag) {
    int c = threadIdx.x % M;
    int rsub = threadIdx.x / M;
    int subs = blockDim.x / M;
    long r0 = ((long)blockIdx.x * subs + rsub) * 8;
    if (r0 >= Nrows) return;
    long roff[8];
#pragma unroll
    for (int j = 0; j < 8; ++j) {
        long r = r0 + j;
        if (r > Nrows - 1) r = Nrows - 1;
        roff[j] = r * (long)K;
    }
    float acc[8] = {0, 0, 0, 0, 0, 0, 0, 0};
    if (*flag) {
        const float* A = (const float*)Araw;
        for (int k = 0; k < K; ++k) {
            float w = b2f(W[(long)k * M + c]);
#pragma unroll
            for (int j = 0; j < 8; ++j) acc[j] += A[roff[j] + k] * w;
        }
    } else {
        const bf16* A = (const bf16*)Araw;
        for (int k = 0; k < K; ++k) {
            float w = b2f(W[(long)k * M + c]);
#pragma unroll
            for (int j = 0; j < 8; ++j) acc[j] += b2f(A[roff[j] + k]) * w;
        }
    }
#pragma unroll
    for (int j = 0; j < 8; ++j)
        if (r0 + j < Nrows) C[(r0 + j) * (long)M + c] = __float2bfloat16(acc[j]);
}

// bf16-A-only variant for internal layers
__global__ void k_gemm_bf16(const bf16* __restrict__ A, const bf16* __restrict__ W,
                            bf16* __restrict__ C, int Nrows, int K, int M) {
    int c = threadIdx.x % M;
    int rsub = threadIdx.x / M;
    int subs = blockDim.x / M;
    long r0 = ((long)blockIdx.x * subs + rsub) * 8;
    if (r0 >= Nrows) return;
    long roff[8];
#pragma unroll
    for (int j = 0; j < 8; ++j) {
        long r = r0 + j;
        if (r > Nrows - 1) r = Nrows - 1;
        roff[j] = r * (long)K;
    }
    float acc[8] = {0, 0, 0, 0, 0, 0, 0, 0};
    for (int k = 0; k < K; ++k) {
        float w = b2f(W[(long)k * M + c]);
#pragma unroll
        for (int j = 0; j < 8; ++j) acc[j] += b2f(A[roff[j] + k]) * w;
    }
#pragma unroll
    for (int j = 0; j < 8; ++j)
        if (r0 + j < Nrows) C[(r0 + j) * (long)M + c] = __float2bfloat16(acc[j]);
}

// ---------------- Edge scores by CSR position, 4 heads x 64 dims ----------------
__global__ void k_edge_score4(const uint2* __restrict__ f, const bf16* __restrict__ a,
                              const int* __restrict__ csr_src, const int* __restrict__ csr_dst,
                              float* __restrict__ ex, int E) {
    int gid = blockIdx.x * blockDim.x + threadIdx.x;
    int p = gid >> 6;
    int lane = threadIdx.x & 63;
    if (p >= E) return;
    int s = csr_src[p], d = csr_dst[p];
    BU4 fs, fd;
    fs.u = f[(long)s * 64 + lane];
    fd.u = f[(long)d * 64 + lane];
    float part = 0.f;
#pragma unroll
    for (int j = 0; j < 4; ++j) {
        float v = b2f(fs.b[j]) + b2f(fd.b[j]);
        v = v > 0.f ? v : SLOPE * v;
        part += v * b2f(a[lane * 4 + j]);
    }
    part += __shfl_down(part, 8, 16);
    part += __shfl_down(part, 4, 16);
    part += __shfl_down(part, 2, 16);
    part += __shfl_down(part, 1, 16);
    if ((lane & 15) == 0) ex[(long)p * 4 + (lane >> 4)] = expf(part);
}

// ---------------- Node aggregate, 4 heads x 64 dims. mode 0: elu; mode 1: +res, elu ----------------
__global__ void k_aggregate4(const uint2* __restrict__ f, const float* __restrict__ ex,
                             const int* __restrict__ rowptr, const int* __restrict__ csr_src,
                             const uint2* __restrict__ res, uint2* __restrict__ out,
                             int N, int mode) {
    int gid = blockIdx.x * blockDim.x + threadIdx.x;
    int n = gid >> 6;
    int lane = threadIdx.x & 63;
    if (n >= N) return;
    int p0 = rowptr[n], p1 = rowptr[n + 1];
    int h = lane >> 4;
    float z = 0.f;
    for (int p = p0; p < p1; ++p) z += ex[(long)p * 4 + h];
    float invz = 1.f / z;
    float acc[4] = {0.f, 0.f, 0.f, 0.f};
    for (int p = p0; p < p1; ++p) {
        float alpha = ex[(long)p * 4 + h] * invz;
        BU4 v;
        v.u = f[(long)csr_src[p] * 64 + lane];
#pragma unroll
        for (int j = 0; j < 4; ++j) acc[j] += alpha * b2f(v.b[j]);
    }
    if (mode == 1) {
        BU4 r;
        r.u = res[(long)n * 64 + lane];
#pragma unroll
        for (int j = 0; j < 4; ++j) acc[j] += b2f(r.b[j]);
    }
    BU4 o;
#pragma unroll
    for (int j = 0; j < 4; ++j) {
        float v = acc[j] > 0.f ? acc[j] : expm1f(acc[j]);
        o.b[j] = __float2bfloat16(v);
    }
    out[(long)n * 64 + lane] = o.u;
}

// ---------------- Final layer: 1 head x 32 dims ----------------
__global__ void k_edge_score_fin(const bf16* __restrict__ f2, const bf16* __restrict__ a2,
                                 const int* __restrict__ csr_src, const int* __restrict__ csr_dst,
                                 float* __restrict__ ex2, int E) {
    int gid = blockIdx.x * blockDim.x + threadIdx.x;
    int p = gid >> 5;
    int sub = threadIdx.x & 31;
    if (p >= E) return;
    int s = csr_src[p], d = csr_dst[p];
    float v = b2f(f2[(long)s * 32 + sub]) + b2f(f2[(long)d * 32 + sub]);
    v = v > 0.f ? v : SLOPE * v;
    float part = v * b2f(a2[sub]);
    part += __shfl_down(part, 16, 32);
    part += __shfl_down(part, 8, 32);
    part += __shfl_down(part, 4, 32);
    part += __shfl_down(part, 2, 32);
    part += __shfl_down(part, 1, 32);
    if (sub == 0) ex2[p] = expf(part);
}

__global__ void k_aggregate_fin(const bf16* __restrict__ f2, const float* __restrict__ ex2,
                                const int* __restrict__ rowptr, const int* __restrict__ csr_src,
                                const bf16* __restrict__ res2, void* __restrict__ outraw,
                                int N, const int* __restrict__ flag) {
    int gid = blockIdx.x * blockDim.x + threadIdx.x;
    int n = gid >> 5;
    int lane = threadIdx.x & 31;
    if (n >= N) return;
    int p0 = rowptr[n], p1 = rowptr[n + 1];
    float z = 0.f;
    for (int p = p0; p < p1; ++p) z += ex2[p];
    float invz = 1.f / z;
    float acc = 0.f;
    for (int p = p0; p < p1; ++p)
        acc += ex2[p] * invz * b2f(f2[(long)csr_src[p] * 32 + lane]);
    acc += b2f(res2[(long)n * 32 + lane]);
    if (*flag) ((float*)outraw)[(long)n * 32 + lane] = acc;
    else       ((bf16*)outraw)[(long)n * 32 + lane] = __float2bfloat16(acc);
}

extern "C" void kernel_launch(void* const* d_in, const int* in_sizes, int n_in,
                              void* d_out, int out_size, void* d_ws, size_t ws_size,
                              hipStream_t stream) {
    const int N = in_sizes[0] / 256;
    const int E = in_sizes[1];

    const void* x     = d_in[0];
    const int*  src   = (const int*)d_in[1];
    const int*  dst   = (const int*)d_in[2];

    // ---- workspace carve (bump allocator, 16B-aligned) ----
    char* w = (char*)d_ws;
    auto alloc = [&](size_t bytes) -> char* {
        char* p = w;
        w += (bytes + 15) & ~(size_t)15;
        return p;
    };
    bf16* hA = (bf16*)alloc((size_t)N * 256 * 2);   // layer0 out / layer1 residual
    bf16* hB = (bf16*)alloc((size_t)N * 256 * 2);   // layer1 out
    bf16* fB = (bf16*)alloc((size_t)N * 256 * 2);   // current f
    char* exbase = alloc((size_t)E * 4 * 4);        // layer scores (fp32 E*4), CSR order
    float* ex = (float*)exbase;
    // final layer aliases onto ex (dead by then): ex2 | f2 | r2
    float* ex2 = (float*)exbase;
    bf16*  f2  = (bf16*)(exbase + (((size_t)E * 4 + 15) & ~(size_t)15));
    bf16*  r2  = (bf16*)((char*)f2 + (((size_t)N * 32 * 2 + 15) & ~(size_t)15));
    int* csr_src = (int*)alloc((size_t)E * 4);
    int* csr_dst = (int*)alloc((size_t)E * 4);
    int* rowptr  = (int*)alloc((size_t)(N + 1) * 4);
    int* cursor  = (int*)alloc((size_t)N * 4);
    // canonical bf16 weights
    bf16* W0c    = (bf16*)alloc((size_t)65536 * 2);
    bf16* W1c    = (bf16*)alloc((size_t)65536 * 2);
    bf16* W2c    = (bf16*)alloc((size_t)8192 * 2);
    bf16* Wr2c   = (bf16*)alloc((size_t)8192 * 2);
    bf16* a0c    = (bf16*)alloc((size_t)256 * 2);
    bf16* a1c    = (bf16*)alloc((size_t)256 * 2);
    bf16* a2c    = (bf16*)alloc((size_t)32 * 2);
    int*  flag   = (int*)alloc(16);

    // ---- dtype detect + weight conversion ----
    k_detect<<<1, 64, 0, stream>>>(x, flag);
    k_convert<<<(65536 + 255) / 256, 256, 0, stream>>>(d_in[3], W0c, 65536, flag);
    k_convert<<<1, 256, 0, stream>>>(d_in[4], a0c, 256, flag);
    k_convert<<<(65536 + 255) / 256, 256, 0, stream>>>(d_in[5], W1c, 65536, flag);
    k_convert<<<1, 256, 0, stream>>>(d_in[6], a1c, 256, flag);
    k_convert<<<(8192 + 255) / 256, 256, 0, stream>>>(d_in[7], W2c, 8192, flag);
    k_convert<<<1, 32, 0, stream>>>(d_in[8], a2c, 32, flag);
    k_convert<<<(8192 + 255) / 256, 256, 0, stream>>>(d_in[9], Wr2c, 8192, flag);

    // ---- CSR build (graph identical for all layers) ----
    hipMemsetAsync(cursor, 0, (size_t)N * 4, stream);
    k_hist<<<(E + 255) / 256, 256, 0, stream>>>(dst, cursor, E);
    k_scan<<<1, 1024, 0, stream>>>(cursor, rowptr, N);
    k_copy_i<<<(N + 255) / 256, 256, 0, stream>>>(rowptr, cursor, N);
    k_scatter<<<(E + 255) / 256, 256, 0, stream>>>(src, dst, cursor, csr_src, csr_dst, E);

    const int egrid4 = (int)(((long)E * 64 + 255) / 256);
    const int egrid1 = (int)(((long)E * 32 + 255) / 256);
    const int ngrid4 = (int)(((long)N * 64 + 255) / 256);
    const int ngrid1 = (int)(((long)N * 32 + 255) / 256);

    // ---- layer 0: f = x@W0; scores; aggregate+elu -> hA ----
    k_gemm_adapt<<<(N + 7) / 8, 256, 0, stream>>>(x, W0c, fB, N, 256, 256, flag);
    k_edge_score4<<<egrid4, 256, 0, stream>>>((const uint2*)fB, a0c, csr_src, csr_dst, ex, E);
    k_aggregate4<<<ngrid4, 256, 0, stream>>>((const uint2*)fB, ex, rowptr, csr_src,
                                             nullptr, (uint2*)hA, N, 0);

    // ---- layer 1: f = hA@W1; scores; aggregate+res(hA)+elu -> hB ----
    k_gemm_bf16<<<(N + 7) / 8, 256, 0, stream>>>(hA, W1c, fB, N, 256, 256);
    k_edge_score4<<<egrid4, 256, 0, stream>>>((const uint2*)fB, a1c, csr_src, csr_dst, ex, E);
    k_aggregate4<<<ngrid4, 256, 0, stream>>>((const uint2*)fB, ex, rowptr, csr_src,
                                             (const uint2*)hA, (uint2*)hB, N, 1);

    // ---- final layer: f2 = hB@W2, r2 = hB@Wres2; scores; aggregate+res -> out ----
    k_gemm_bf16<<<(N + 63) / 64, 256, 0, stream>>>(hB, W2c, f2, N, 256, 32);
    k_gemm_bf16<<<(N + 63) / 64, 256, 0, stream>>>(hB, Wr2c, r2, N, 256, 32);
    k_edge_score_fin<<<egrid1, 256, 0, stream>>>(f2, a2c, csr_src, csr_dst, ex2, E);
    k_aggregate_fin<<<ngrid1, 256, 0, stream>>>(f2, ex2, rowptr, csr_src, r2, d_out, N, flag);
}

// Round 4
// 687.682 us; speedup vs baseline: 2.7945x; 2.7945x over previous
//
#include <hip/hip_runtime.h>
#include <hip/hip_bf16.h>

typedef __hip_bfloat16 bf16;
#define SLOPE 0.2f

__device__ __forceinline__ float b2f(bf16 v) { return __bfloat162float(v); }

union BU4 { uint2 u; bf16 b[4]; };

typedef __attribute__((ext_vector_type(8))) short bf16x8;
typedef __attribute__((ext_vector_type(16))) float f32x16;

// ---------------- dtype detect: flag=0 -> buffers are bf16, flag=1 -> fp32 ----------------
__global__ void k_detect(const void* __restrict__ x, int* __restrict__ flag) {
    const unsigned short* u = (const unsigned short*)x;
    int tid = threadIdx.x;
    int nice = 0;
    for (int i = tid; i < 256; i += 64) {
        unsigned int bits = ((unsigned int)u[2 * i]) << 16;
        float v = __uint_as_float(bits);
        float av = fabsf(v);
        if (v == 0.0f || (av > 1e-6f && av < 100.0f)) ++nice;
    }
    for (int off = 32; off > 0; off >>= 1) nice += __shfl_down(nice, off, 64);
    if (tid == 0) *flag = (nice >= 192) ? 0 : 1;
}

__global__ void k_convert(const void* __restrict__ src, bf16* __restrict__ dst, int n,
                          const int* __restrict__ flag) {
    int i = blockIdx.x * blockDim.x + threadIdx.x;
    if (i >= n) return;
    if (*flag) dst[i] = __float2bfloat16(((const float*)src)[i]);
    else       dst[i] = ((const bf16*)src)[i];
}

// transpose W[K,M] -> Wt[M,K] (bf16), adaptive input dtype
__global__ void k_wtrans(const void* __restrict__ raw, bf16* __restrict__ Wt, int K, int M,
                         const int* __restrict__ flag) {
    int idx = blockIdx.x * blockDim.x + threadIdx.x;
    if (idx >= K * M) return;
    int k = idx / M, m = idx % M;
    float v = (*flag) ? ((const float*)raw)[idx] : b2f(((const bf16*)raw)[idx]);
    Wt[(long)m * K + k] = __float2bfloat16(v);
}

// combined final weights: Wt2f[64][256]; rows 0..31 = W2^T, rows 32..63 = Wres2^T
__global__ void k_wtrans2(const void* __restrict__ W2raw, const void* __restrict__ Wr2raw,
                          bf16* __restrict__ Wt, const int* __restrict__ flag) {
    int idx = blockIdx.x * blockDim.x + threadIdx.x;
    if (idx >= 64 * 256) return;
    int j = idx >> 8, k = idx & 255;
    const void* src = (j < 32) ? W2raw : Wr2raw;
    int jj = j & 31;
    float v = (*flag) ? ((const float*)src)[k * 32 + jj] : b2f(((const bf16*)src)[k * 32 + jj]);
    Wt[idx] = __float2bfloat16(v);
}

// ---------------- CSR build ----------------
__global__ void k_hist(const int* __restrict__ dst, int* __restrict__ cnt, int E) {
    int e = blockIdx.x * blockDim.x + threadIdx.x;
    if (e < E) atomicAdd(&cnt[dst[e]], 1);
}

__global__ void k_scan(const int* __restrict__ cnt, int* __restrict__ rowptr, int n) {
    __shared__ int sh[1024];
    int tid = threadIdx.x;
    int chunk = (n + 1023) >> 10;
    int start = tid * chunk;
    int end = min(start + chunk, n);
    int s = 0;
    for (int i = start; i < end; ++i) s += cnt[i];
    sh[tid] = s;
    __syncthreads();
    for (int off = 1; off < 1024; off <<= 1) {
        int v = (tid >= off) ? sh[tid - off] : 0;
        __syncthreads();
        sh[tid] += v;
        __syncthreads();
    }
    int base = (tid > 0) ? sh[tid - 1] : 0;
    for (int i = start; i < end; ++i) { rowptr[i] = base; base += cnt[i]; }
    if (tid == 1023) rowptr[n] = sh[1023];
}

__global__ void k_copy_i(const int* __restrict__ a, int* __restrict__ b, int n) {
    int i = blockIdx.x * blockDim.x + threadIdx.x;
    if (i < n) b[i] = a[i];
}

__global__ void k_scatter(const int* __restrict__ src, const int* __restrict__ dst,
                          int* __restrict__ cursor, int* __restrict__ csr_src, int E) {
    int e = blockIdx.x * blockDim.x + threadIdx.x;
    if (e < E) {
        int p = atomicAdd(&cursor[dst[e]], 1);
        csr_src[p] = src[e];
    }
}

// ---------------- MFMA GEMM: C[N,256](bf16) = A[N,256](bf16) @ W, Wt[n][k] pre-transposed ----
// block 256 = 4 waves as 2 (rows) x 2 (cols); wave = 32 rows x 128 cols (4 col-tiles)
__global__ void k_gemm_mfma(const bf16* __restrict__ A, const bf16* __restrict__ Wt,
                            bf16* __restrict__ C, int Nrows) {
    int warp = threadIdx.x >> 6;
    int lane = threadIdx.x & 63;
    int wr = warp >> 1;
    int wc = warp & 1;
    long rowBase = (long)blockIdx.x * 64 + wr * 32;
    int colBase = wc * 128;
    int m = lane & 31;
    int g = lane >> 5;
    long r = rowBase + m;
    if (r >= Nrows) r = Nrows - 1;
    const short* Arow = (const short*)A + r * 256 + g * 8;
    const short* Wts = (const short*)Wt;
    f32x16 acc[4] = {};
    for (int k0 = 0; k0 < 256; k0 += 16) {
        bf16x8 af = *(const bf16x8*)(Arow + k0);
#pragma unroll
        for (int ct = 0; ct < 4; ++ct) {
            int n = colBase + ct * 32 + m;
            bf16x8 bfr = *(const bf16x8*)(Wts + (long)n * 256 + k0 + g * 8);
            acc[ct] = __builtin_amdgcn_mfma_f32_32x32x16_bf16(af, bfr, acc[ct], 0, 0, 0);
        }
    }
#pragma unroll
    for (int ct = 0; ct < 4; ++ct) {
#pragma unroll
        for (int i = 0; i < 16; ++i) {
            long row = rowBase + (i & 3) + 8 * (i >> 2) + 4 * g;
            if (row < Nrows)
                C[row * 256 + colBase + ct * 32 + m] = __float2bfloat16(acc[ct][i]);
        }
    }
}

// C[N,64] = A[N,256] @ (Wt2f[64][256])^T ; block 4 waves = 128 rows x 64 cols
__global__ void k_gemm_mfma64(const bf16* __restrict__ A, const bf16* __restrict__ Wt,
                              bf16* __restrict__ C, int Nrows) {
    int warp = threadIdx.x >> 6;
    int lane = threadIdx.x & 63;
    long rowBase = (long)blockIdx.x * 128 + warp * 32;
    int m = lane & 31;
    int g = lane >> 5;
    long r = rowBase + m;
    if (r >= Nrows) r = Nrows - 1;
    const short* Arow = (const short*)A + r * 256 + g * 8;
    const short* Wts = (const short*)Wt;
    f32x16 acc[2] = {};
    for (int k0 = 0; k0 < 256; k0 += 16) {
        bf16x8 af = *(const bf16x8*)(Arow + k0);
#pragma unroll
        for (int ct = 0; ct < 2; ++ct) {
            bf16x8 bfr = *(const bf16x8*)(Wts + (long)(ct * 32 + m) * 256 + k0 + g * 8);
            acc[ct] = __builtin_amdgcn_mfma_f32_32x32x16_bf16(af, bfr, acc[ct], 0, 0, 0);
        }
    }
#pragma unroll
    for (int ct = 0; ct < 2; ++ct) {
#pragma unroll
        for (int i = 0; i < 16; ++i) {
            long row = rowBase + (i & 3) + 8 * (i >> 2) + 4 * g;
            if (row < Nrows)
                C[row * 64 + ct * 32 + m] = __float2bfloat16(acc[ct][i]);
        }
    }
}

// ---------------- Fused GATv2 layer: score + softmax + aggregate (+res) + elu ----------------
// one wave per node; 4 heads x 64 dims; softmax normalized at the end (no ex buffer)
__global__ void k_gat_fused(const uint2* __restrict__ f, const bf16* __restrict__ a,
                            const int* __restrict__ rowptr, const int* __restrict__ csr_src,
                            const uint2* __restrict__ res, uint2* __restrict__ out,
                            int N, int mode) {
    int n = (blockIdx.x * blockDim.x + threadIdx.x) >> 6;
    int lane = threadIdx.x & 63;
    if (n >= N) return;
    BU4 fdu; fdu.u = f[(long)n * 64 + lane];
    float fd[4], av[4];
#pragma unroll
    for (int j = 0; j < 4; ++j) {
        fd[j] = b2f(fdu.b[j]);
        av[j] = b2f(a[lane * 4 + j]);
    }
    int p0 = rowptr[n], p1 = rowptr[n + 1];
    float z = 0.f, acc[4] = {0.f, 0.f, 0.f, 0.f};
    // self-loops guarantee p1 > p0
    uint2 fsu = f[(long)csr_src[p0] * 64 + lane];
    for (int p = p0; p < p1; ++p) {
        uint2 fsn = make_uint2(0, 0);
        if (p + 1 < p1) fsn = f[(long)csr_src[p + 1] * 64 + lane];
        BU4 v; v.u = fsu;
        float fs[4], t = 0.f;
#pragma unroll
        for (int j = 0; j < 4; ++j) {
            fs[j] = b2f(v.b[j]);
            float u = fs[j] + fd[j];
            u = u > 0.f ? u : SLOPE * u;
            t += u * av[j];
        }
        t += __shfl_xor(t, 1, 16);
        t += __shfl_xor(t, 2, 16);
        t += __shfl_xor(t, 4, 16);
        t += __shfl_xor(t, 8, 16);
        float wgt = __expf(t);
        z += wgt;
#pragma unroll
        for (int j = 0; j < 4; ++j) acc[j] += wgt * fs[j];
        fsu = fsn;
    }
    float invz = 1.f / z;
#pragma unroll
    for (int j = 0; j < 4; ++j) acc[j] *= invz;
    if (mode == 1) {
        BU4 rr; rr.u = res[(long)n * 64 + lane];
#pragma unroll
        for (int j = 0; j < 4; ++j) acc[j] += b2f(rr.b[j]);
    }
    BU4 o;
#pragma unroll
    for (int j = 0; j < 4; ++j) {
        float v = acc[j] > 0.f ? acc[j] : expm1f(acc[j]);
        o.b[j] = __float2bfloat16(v);
    }
    out[(long)n * 64 + lane] = o.u;
}

// ---------------- Fused final layer: fr2[N][64] = [f2 | r2]; half-wave per node ----------------
__global__ void k_gat_fused_fin(const bf16* __restrict__ fr2, const bf16* __restrict__ a2,
                                const int* __restrict__ rowptr, const int* __restrict__ csr_src,
                                void* __restrict__ outraw, int N, const int* __restrict__ flag) {
    int gid = blockIdx.x * blockDim.x + threadIdx.x;
    int n = gid >> 5;
    int il = threadIdx.x & 31;
    if (n >= N) return;
    float fd = b2f(fr2[(long)n * 64 + il]);
    float rv = b2f(fr2[(long)n * 64 + 32 + il]);
    float a2v = b2f(a2[il]);
    int p0 = rowptr[n], p1 = rowptr[n + 1];
    float z = 0.f, acc = 0.f;
    float fs = b2f(fr2[(long)csr_src[p0] * 64 + il]);
    for (int p = p0; p < p1; ++p) {
        float fsn = 0.f;
        if (p + 1 < p1) fsn = b2f(fr2[(long)csr_src[p + 1] * 64 + il]);
        float u = fs + fd;
        u = u > 0.f ? u : SLOPE * u;
        float t = u * a2v;
        t += __shfl_xor(t, 1, 32);
        t += __shfl_xor(t, 2, 32);
        t += __shfl_xor(t, 4, 32);
        t += __shfl_xor(t, 8, 32);
        t += __shfl_xor(t, 16, 32);
        float wgt = __expf(t);
        z += wgt;
        acc += wgt * fs;
        fs = fsn;
    }
    float o = acc / z + rv;
    if (*flag) ((float*)outraw)[(long)n * 32 + il] = o;
    else       ((bf16*)outraw)[(long)n * 32 + il] = __float2bfloat16(o);
}

extern "C" void kernel_launch(void* const* d_in, const int* in_sizes, int n_in,
                              void* d_out, int out_size, void* d_ws, size_t ws_size,
                              hipStream_t stream) {
    const int N = in_sizes[0] / 256;
    const int E = in_sizes[1];

    const void* x   = d_in[0];
    const int*  src = (const int*)d_in[1];
    const int*  dst = (const int*)d_in[2];

    // ---- workspace carve ----
    char* w = (char*)d_ws;
    auto alloc = [&](size_t bytes) -> char* {
        char* p = w;
        w += (bytes + 15) & ~(size_t)15;
        return p;
    };
    bf16* buf0 = (bf16*)alloc((size_t)N * 256 * 2);  // xb, later hB (xb dead after GEMM0)
    bf16* buf1 = (bf16*)alloc((size_t)N * 256 * 2);  // hA
    bf16* buf2 = (bf16*)alloc((size_t)N * 256 * 2);  // fB, later fr2 (fB dead after layer1 agg)
    int* csr_src = (int*)alloc((size_t)E * 4);
    int* rowptr  = (int*)alloc((size_t)(N + 1) * 4);
    int* cursor  = (int*)alloc((size_t)N * 4);
    bf16* Wt0  = (bf16*)alloc((size_t)65536 * 2);
    bf16* Wt1  = (bf16*)alloc((size_t)65536 * 2);
    bf16* Wt2f = (bf16*)alloc((size_t)64 * 256 * 2);
    bf16* a0c  = (bf16*)alloc((size_t)256 * 2);
    bf16* a1c  = (bf16*)alloc((size_t)256 * 2);
    bf16* a2c  = (bf16*)alloc((size_t)32 * 2);
    int*  flag = (int*)alloc(16);

    bf16* xb  = buf0;
    bf16* hA  = buf1;
    bf16* fB  = buf2;
    bf16* hB  = buf0;
    bf16* fr2 = buf2;

    // ---- dtype detect + weight prep ----
    k_detect<<<1, 64, 0, stream>>>(x, flag);
    k_convert<<<(N * 256 + 255) / 256, 256, 0, stream>>>(x, xb, N * 256, flag);
    k_wtrans<<<(65536 + 255) / 256, 256, 0, stream>>>(d_in[3], Wt0, 256, 256, flag);
    k_wtrans<<<(65536 + 255) / 256, 256, 0, stream>>>(d_in[5], Wt1, 256, 256, flag);
    k_wtrans2<<<(64 * 256 + 255) / 256, 256, 0, stream>>>(d_in[7], d_in[9], Wt2f, flag);
    k_convert<<<1, 256, 0, stream>>>(d_in[4], a0c, 256, flag);
    k_convert<<<1, 256, 0, stream>>>(d_in[6], a1c, 256, flag);
    k_convert<<<1, 32, 0, stream>>>(d_in[8], a2c, 32, flag);

    // ---- CSR build ----
    hipMemsetAsync(cursor, 0, (size_t)N * 4, stream);
    k_hist<<<(E + 255) / 256, 256, 0, stream>>>(dst, cursor, E);
    k_scan<<<1, 1024, 0, stream>>>(cursor, rowptr, N);
    k_copy_i<<<(N + 255) / 256, 256, 0, stream>>>(rowptr, cursor, N);
    k_scatter<<<(E + 255) / 256, 256, 0, stream>>>(src, dst, cursor, csr_src, E);

    const int ngrid4 = (int)(((long)N * 64 + 255) / 256);
    const int ngrid1 = (int)(((long)N * 32 + 255) / 256);

    // ---- layer 0 ----
    k_gemm_mfma<<<(N + 63) / 64, 256, 0, stream>>>(xb, Wt0, fB, N);
    k_gat_fused<<<ngrid4, 256, 0, stream>>>((const uint2*)fB, a0c, rowptr, csr_src,
                                            nullptr, (uint2*)hA, N, 0);
    // ---- layer 1 ----
    k_gemm_mfma<<<(N + 63) / 64, 256, 0, stream>>>(hA, Wt1, fB, N);
    k_gat_fused<<<ngrid4, 256, 0, stream>>>((const uint2*)fB, a1c, rowptr, csr_src,
                                            (const uint2*)hA, (uint2*)hB, N, 1);
    // ---- final layer ----
    k_gemm_mfma64<<<(N + 127) / 128, 256, 0, stream>>>(hB, Wt2f, fr2, N);
    k_gat_fused_fin<<<ngrid1, 256, 0, stream>>>(fr2, a2c, rowptr, csr_src, d_out, N, flag);
}

// Round 6
// 548.948 us; speedup vs baseline: 3.5008x; 1.2527x over previous
//
#include <hip/hip_runtime.h>
#include <hip/hip_bf16.h>

typedef __hip_bfloat16 bf16;
#define SLOPE 0.2f

__device__ __forceinline__ float b2f(bf16 v) { return __bfloat162float(v); }
__device__ __forceinline__ short f2b_raw(float x) {
    bf16 b = __float2bfloat16(x);
    return *reinterpret_cast<short*>(&b);
}

typedef __attribute__((ext_vector_type(8))) short bf16x8;
typedef __attribute__((ext_vector_type(16))) float f32x16;

union Q16 { uint4 q[2]; unsigned u[8]; };

__device__ __forceinline__ void unpack16(const Q16& x, float* v) {
#pragma unroll
    for (int i = 0; i < 8; ++i) {
        v[2 * i]     = __uint_as_float(x.u[i] << 16);
        v[2 * i + 1] = __uint_as_float(x.u[i] & 0xffff0000u);
    }
}

// ---------------- dtype detect: flag=0 -> bf16 inputs, flag=1 -> fp32 ----------------
__global__ void k_detect(const void* __restrict__ x, int* __restrict__ flag) {
    const unsigned short* u = (const unsigned short*)x;
    int tid = threadIdx.x;
    int nice = 0;
    for (int i = tid; i < 256; i += 64) {
        unsigned int bits = ((unsigned int)u[2 * i]) << 16;
        float v = __uint_as_float(bits);
        float av = fabsf(v);
        if (v == 0.0f || (av > 1e-6f && av < 100.0f)) ++nice;
    }
    for (int off = 32; off > 0; off >>= 1) nice += __shfl_down(nice, off, 64);
    if (tid == 0) *flag = (nice >= 192) ? 0 : 1;
}

__global__ void k_convert(const void* __restrict__ src, bf16* __restrict__ dst, int n,
                          const int* __restrict__ flag) {
    int i = blockIdx.x * blockDim.x + threadIdx.x;
    if (i >= n) return;
    if (*flag) dst[i] = __float2bfloat16(((const float*)src)[i]);
    else       dst[i] = ((const bf16*)src)[i];
}

// transpose W[K,M] -> Wt[M,K] (bf16)
__global__ void k_wtrans(const void* __restrict__ raw, bf16* __restrict__ Wt, int K, int M,
                         const int* __restrict__ flag) {
    int idx = blockIdx.x * blockDim.x + threadIdx.x;
    if (idx >= K * M) return;
    int k = idx / M, m = idx % M;
    float v = (*flag) ? ((const float*)raw)[idx] : b2f(((const bf16*)raw)[idx]);
    Wt[(long)m * K + k] = __float2bfloat16(v);
}

// combined final weights: Wt2f[64][256]; rows 0..31 = W2^T, rows 32..63 = Wres2^T
__global__ void k_wtrans2(const void* __restrict__ W2raw, const void* __restrict__ Wr2raw,
                          bf16* __restrict__ Wt, const int* __restrict__ flag) {
    int idx = blockIdx.x * blockDim.x + threadIdx.x;
    if (idx >= 64 * 256) return;
    int j = idx >> 8, k = idx & 255;
    const void* src = (j < 32) ? W2raw : Wr2raw;
    int jj = j & 31;
    float v = (*flag) ? ((const float*)src)[k * 32 + jj] : b2f(((const bf16*)src)[k * 32 + jj]);
    Wt[idx] = __float2bfloat16(v);
}

// ---------------- CSR build ----------------
__global__ void k_hist(const int* __restrict__ dst, int* __restrict__ cnt, int E) {
    int e = blockIdx.x * blockDim.x + threadIdx.x;
    if (e < E) atomicAdd(&cnt[dst[e]], 1);
}

// phase A: per-block (1024 elems) sums
__global__ void k_bsum(const int* __restrict__ cnt, int* __restrict__ bsum, int n) {
    __shared__ int sh[256];
    int base = blockIdx.x * 1024 + threadIdx.x * 4;
    int s = 0;
#pragma unroll
    for (int k = 0; k < 4; ++k) { int i = base + k; if (i < n) s += cnt[i]; }
    sh[threadIdx.x] = s;
    __syncthreads();
    for (int off = 128; off > 0; off >>= 1) {
        if (threadIdx.x < off) sh[threadIdx.x] += sh[threadIdx.x + off];
        __syncthreads();
    }
    if (threadIdx.x == 0) bsum[blockIdx.x] = sh[0];
}

// phase B: exclusive scan of B partials (B <= 1024), single block
__global__ void k_bscan(int* __restrict__ bsum, int B) {
    __shared__ int sh[1024];
    int t = threadIdx.x;
    int v = (t < B) ? bsum[t] : 0;
    sh[t] = v;
    __syncthreads();
    for (int off = 1; off < 1024; off <<= 1) {
        int u = (t >= off) ? sh[t - off] : 0;
        __syncthreads();
        sh[t] += u;
        __syncthreads();
    }
    if (t < B) bsum[t] = sh[t] - v;
}

// phase C: write rowptr + cursor (exclusive prefix)
__global__ void k_scanwrite(const int* __restrict__ cnt, const int* __restrict__ bsum,
                            int* __restrict__ rowptr, int* __restrict__ cursor, int n, int E) {
    __shared__ int sh[256];
    int base = blockIdx.x * 1024 + threadIdx.x * 4;
    int loc[4];
    int s = 0;
#pragma unroll
    for (int k = 0; k < 4; ++k) {
        int i = base + k;
        loc[k] = (i < n) ? cnt[i] : 0;
        s += loc[k];
    }
    sh[threadIdx.x] = s;
    __syncthreads();
    for (int off = 1; off < 256; off <<= 1) {
        int u = (threadIdx.x >= off) ? sh[threadIdx.x - off] : 0;
        __syncthreads();
        sh[threadIdx.x] += u;
        __syncthreads();
    }
    int run = bsum[blockIdx.x] + sh[threadIdx.x] - s;
#pragma unroll
    for (int k = 0; k < 4; ++k) {
        int i = base + k;
        if (i < n) { rowptr[i] = run; cursor[i] = run; run += loc[k]; }
    }
    if (blockIdx.x == 0 && threadIdx.x == 0) rowptr[n] = E;
}

__global__ void k_scatter(const int* __restrict__ src, const int* __restrict__ dst,
                          int* __restrict__ cursor, int* __restrict__ csr_src, int E) {
    int e = blockIdx.x * blockDim.x + threadIdx.x;
    if (e < E) {
        int p = atomicAdd(&cursor[dst[e]], 1);
        csr_src[p] = src[e];
    }
}

// ---------------- MFMA GEMM: C[N,256](bf16) = A[N,256] @ W; Wt[n][k] pre-transposed ----
// ADAPT=1: A dtype chosen by flag (external input). ADAPT=0: A is always bf16 (internal).
// block 256 = 2x2 waves; wave = 32 rows x 128 cols
template <int ADAPT>
__global__ void k_gemm_mfma(const void* __restrict__ A, const bf16* __restrict__ Wt,
                            bf16* __restrict__ C, int Nrows, const int* __restrict__ flag) {
    int warp = threadIdx.x >> 6;
    int lane = threadIdx.x & 63;
    int wr = warp >> 1;
    int wc = warp & 1;
    long rowBase = (long)blockIdx.x * 64 + wr * 32;
    int colBase = wc * 128;
    int m = lane & 31;
    int g = lane >> 5;
    long r = rowBase + m;
    if (r >= Nrows) r = Nrows - 1;
    int isf32 = ADAPT ? *flag : 0;
    const short* Ab = (const short*)A + r * 256 + g * 8;
    const float* Af = (const float*)A + r * 256 + g * 8;
    const short* Wts = (const short*)Wt;
    f32x16 acc[4] = {};
    for (int k0 = 0; k0 < 256; k0 += 16) {
        bf16x8 af;
        if (ADAPT && isf32) {
            float4 x0 = *(const float4*)(Af + k0);
            float4 x1 = *(const float4*)(Af + k0 + 4);
            union { bf16x8 v; short s[8]; } t;
            t.s[0] = f2b_raw(x0.x); t.s[1] = f2b_raw(x0.y);
            t.s[2] = f2b_raw(x0.z); t.s[3] = f2b_raw(x0.w);
            t.s[4] = f2b_raw(x1.x); t.s[5] = f2b_raw(x1.y);
            t.s[6] = f2b_raw(x1.z); t.s[7] = f2b_raw(x1.w);
            af = t.v;
        } else {
            af = *(const bf16x8*)(Ab + k0);
        }
#pragma unroll
        for (int ct = 0; ct < 4; ++ct) {
            int n = colBase + ct * 32 + m;
            bf16x8 bfr = *(const bf16x8*)(Wts + (long)n * 256 + k0 + g * 8);
            acc[ct] = __builtin_amdgcn_mfma_f32_32x32x16_bf16(af, bfr, acc[ct], 0, 0, 0);
        }
    }
#pragma unroll
    for (int ct = 0; ct < 4; ++ct) {
#pragma unroll
        for (int i = 0; i < 16; ++i) {
            long row = rowBase + (i & 3) + 8 * (i >> 2) + 4 * g;
            if (row < Nrows)
                C[row * 256 + colBase + ct * 32 + m] = __float2bfloat16(acc[ct][i]);
        }
    }
}

// C[N,64] = A[N,256](bf16) @ (Wt2f[64][256])^T ; block 4 waves = 128 rows x 64 cols
__global__ void k_gemm_mfma64(const bf16* __restrict__ A, const bf16* __restrict__ Wt,
                              bf16* __restrict__ C, int Nrows) {
    int warp = threadIdx.x >> 6;
    int lane = threadIdx.x & 63;
    long rowBase = (long)blockIdx.x * 128 + warp * 32;
    int m = lane & 31;
    int g = lane >> 5;
    long r = rowBase + m;
    if (r >= Nrows) r = Nrows - 1;
    const short* Arow = (const short*)A + r * 256 + g * 8;
    const short* Wts = (const short*)Wt;
    f32x16 acc[2] = {};
    for (int k0 = 0; k0 < 256; k0 += 16) {
        bf16x8 af = *(const bf16x8*)(Arow + k0);
#pragma unroll
        for (int ct = 0; ct < 2; ++ct) {
            bf16x8 bfr = *(const bf16x8*)(Wts + (long)(ct * 32 + m) * 256 + k0 + g * 8);
            acc[ct] = __builtin_amdgcn_mfma_f32_32x32x16_bf16(af, bfr, acc[ct], 0, 0, 0);
        }
    }
#pragma unroll
    for (int ct = 0; ct < 2; ++ct) {
#pragma unroll
        for (int i = 0; i < 16; ++i) {
            long row = rowBase + (i & 3) + 8 * (i >> 2) + 4 * g;
            if (row < Nrows)
                C[row * 64 + ct * 32 + m] = __float2bfloat16(acc[ct][i]);
        }
    }
}

// ---------------- Fused GATv2 layer: 4 edges/iteration, 16 lanes/edge, 16 dims/lane ------
// wave = node n; lane = j*16+l: edge-slot j=lane>>4, dim-chunk l=lane&15 (dims 16l..16l+16)
// head of lane = l>>2 (4 lanes per head). Softmax normalized at the end.
__global__ void k_gat_fused(const uint4* __restrict__ f, const bf16* __restrict__ a,
                            const int* __restrict__ rowptr, const int* __restrict__ csr_src,
                            const uint4* __restrict__ res, uint4* __restrict__ out,
                            int N, int mode) {
    int n = (blockIdx.x * blockDim.x + threadIdx.x) >> 6;
    int lane = threadIdx.x & 63;
    if (n >= N) return;
    int j = lane >> 4, l = lane & 15;

    Q16 fdq, aq;
    fdq.q[0] = f[(long)n * 32 + 2 * l];
    fdq.q[1] = f[(long)n * 32 + 2 * l + 1];
    aq.q[0] = ((const uint4*)a)[2 * l];
    aq.q[1] = ((const uint4*)a)[2 * l + 1];
    float fd[16], av[16];
    unpack16(fdq, fd);
    unpack16(aq, av);

    int p0 = rowptr[n], p1 = rowptr[n + 1];
    int iters = (p1 - p0 + 3) >> 2;
    float z = 0.f, acc[16] = {};

    int p = p0 + j;
    Q16 cur, nxt;
    {
        int s = csr_src[min(p, p1 - 1)];
        cur.q[0] = f[(long)s * 32 + 2 * l];
        cur.q[1] = f[(long)s * 32 + 2 * l + 1];
    }
    for (int i = 0; i < iters; ++i) {
        if (i + 1 < iters) {
            int s = csr_src[min(p + 4, p1 - 1)];
            nxt.q[0] = f[(long)s * 32 + 2 * l];
            nxt.q[1] = f[(long)s * 32 + 2 * l + 1];
        }
        float fs[16];
        unpack16(cur, fs);
        float t = 0.f;
#pragma unroll
        for (int k = 0; k < 16; ++k) {
            float u = fs[k] + fd[k];
            u = fmaf(fminf(u, 0.f), SLOPE, fmaxf(u, 0.f));
            t = fmaf(u, av[k], t);
        }
        t += __shfl_xor(t, 1);
        t += __shfl_xor(t, 2);
        float wgt = (p < p1) ? __expf(t) : 0.f;
        z += wgt;
#pragma unroll
        for (int k = 0; k < 16; ++k) acc[k] = fmaf(wgt, fs[k], acc[k]);
        cur = nxt;
        p += 4;
    }
    // combine the 4 edge-groups
    z += __shfl_xor(z, 16);
    z += __shfl_xor(z, 32);
#pragma unroll
    for (int k = 0; k < 16; ++k) {
        acc[k] += __shfl_xor(acc[k], 16);
        acc[k] += __shfl_xor(acc[k], 32);
    }
    if (j == 0) {
        float invz = 1.f / z;
        float o[16];
        if (mode == 1) {
            Q16 rq;
            rq.q[0] = res[(long)n * 32 + 2 * l];
            rq.q[1] = res[(long)n * 32 + 2 * l + 1];
            float rv[16];
            unpack16(rq, rv);
#pragma unroll
            for (int k = 0; k < 16; ++k) o[k] = fmaf(acc[k], invz, rv[k]);
        } else {
#pragma unroll
            for (int k = 0; k < 16; ++k) o[k] = acc[k] * invz;
        }
        union { uint4 q[2]; short s[16]; } ob;
#pragma unroll
        for (int k = 0; k < 16; ++k) {
            float v = o[k] > 0.f ? o[k] : expm1f(o[k]);
            ob.s[k] = f2b_raw(v);
        }
        out[(long)n * 32 + 2 * l] = ob.q[0];
        out[(long)n * 32 + 2 * l + 1] = ob.q[1];
    }
}

// ---------------- Fused final layer: fr2[N][64] = [f2 | r2]; half-wave per node ----------------
__global__ void k_gat_fused_fin(const bf16* __restrict__ fr2, const bf16* __restrict__ a2,
                                const int* __restrict__ rowptr, const int* __restrict__ csr_src,
                                void* __restrict__ outraw, int N, const int* __restrict__ flag) {
    int gid = blockIdx.x * blockDim.x + threadIdx.x;
    int n = gid >> 5;
    int il = threadIdx.x & 31;
    if (n >= N) return;
    float fd = b2f(fr2[(long)n * 64 + il]);
    float rv = b2f(fr2[(long)n * 64 + 32 + il]);
    float a2v = b2f(a2[il]);
    int p0 = rowptr[n], p1 = rowptr[n + 1];
    float z = 0.f, acc = 0.f;
    float fs = b2f(fr2[(long)csr_src[p0] * 64 + il]);
    for (int p = p0; p < p1; ++p) {
        float fsn = 0.f;
        if (p + 1 < p1) fsn = b2f(fr2[(long)csr_src[p + 1] * 64 + il]);
        float u = fs + fd;
        u = u > 0.f ? u : SLOPE * u;
        float t = u * a2v;
        t += __shfl_xor(t, 1, 32);
        t += __shfl_xor(t, 2, 32);
        t += __shfl_xor(t, 4, 32);
        t += __shfl_xor(t, 8, 32);
        t += __shfl_xor(t, 16, 32);
        float wgt = __expf(t);
        z += wgt;
        acc += wgt * fs;
        fs = fsn;
    }
    float o = acc / z + rv;
    if (*flag) ((float*)outraw)[(long)n * 32 + il] = o;
    else       ((bf16*)outraw)[(long)n * 32 + il] = __float2bfloat16(o);
}

extern "C" void kernel_launch(void* const* d_in, const int* in_sizes, int n_in,
                              void* d_out, int out_size, void* d_ws, size_t ws_size,
                              hipStream_t stream) {
    const int N = in_sizes[0] / 256;
    const int E = in_sizes[1];

    const void* x   = d_in[0];
    const int*  src = (const int*)d_in[1];
    const int*  dst = (const int*)d_in[2];

    // ---- workspace carve ----
    char* w = (char*)d_ws;
    auto alloc = [&](size_t bytes) -> char* {
        char* p = w;
        w += (bytes + 15) & ~(size_t)15;
        return p;
    };
    bf16* buf0 = (bf16*)alloc((size_t)N * 256 * 2);  // hB
    bf16* buf1 = (bf16*)alloc((size_t)N * 256 * 2);  // hA
    bf16* buf2 = (bf16*)alloc((size_t)N * 256 * 2);  // fB / fr2
    int* csr_src = (int*)alloc((size_t)E * 4);
    int* rowptr  = (int*)alloc((size_t)(N + 1) * 4);
    int* cursor  = (int*)alloc((size_t)N * 4);
    int* cnt     = (int*)alloc((size_t)N * 4);
    int* bsum    = (int*)alloc((size_t)1024 * 4);
    bf16* Wt0  = (bf16*)alloc((size_t)65536 * 2);
    bf16* Wt1  = (bf16*)alloc((size_t)65536 * 2);
    bf16* Wt2f = (bf16*)alloc((size_t)64 * 256 * 2);
    bf16* a0c  = (bf16*)alloc((size_t)256 * 2);
    bf16* a1c  = (bf16*)alloc((size_t)256 * 2);
    bf16* a2c  = (bf16*)alloc((size_t)32 * 2);
    int*  flag = (int*)alloc(16);

    bf16* hA  = buf1;
    bf16* fB  = buf2;
    bf16* hB  = buf0;
    bf16* fr2 = buf2;

    // ---- dtype detect + weight prep ----
    k_detect<<<1, 64, 0, stream>>>(x, flag);
    k_wtrans<<<(65536 + 255) / 256, 256, 0, stream>>>(d_in[3], Wt0, 256, 256, flag);
    k_wtrans<<<(65536 + 255) / 256, 256, 0, stream>>>(d_in[5], Wt1, 256, 256, flag);
    k_wtrans2<<<(64 * 256 + 255) / 256, 256, 0, stream>>>(d_in[7], d_in[9], Wt2f, flag);
    k_convert<<<1, 256, 0, stream>>>(d_in[4], a0c, 256, flag);
    k_convert<<<1, 256, 0, stream>>>(d_in[6], a1c, 256, flag);
    k_convert<<<1, 32, 0, stream>>>(d_in[8], a2c, 32, flag);

    // ---- CSR build ----
    const int B = (N + 1023) / 1024;
    hipMemsetAsync(cnt, 0, (size_t)N * 4, stream);
    k_hist<<<(E + 255) / 256, 256, 0, stream>>>(dst, cnt, E);
    k_bsum<<<B, 256, 0, stream>>>(cnt, bsum, N);
    k_bscan<<<1, 1024, 0, stream>>>(bsum, B);
    k_scanwrite<<<B, 256, 0, stream>>>(cnt, bsum, rowptr, cursor, N, E);
    k_scatter<<<(E + 255) / 256, 256, 0, stream>>>(src, dst, cursor, csr_src, E);

    const int ngrid4 = (int)(((long)N * 64 + 255) / 256);
    const int ngrid1 = (int)(((long)N * 32 + 255) / 256);

    // ---- layer 0 (x read directly, fp32 converted in-flight) ----
    k_gemm_mfma<1><<<(N + 63) / 64, 256, 0, stream>>>(x, Wt0, fB, N, flag);
    k_gat_fused<<<ngrid4, 256, 0, stream>>>((const uint4*)fB, a0c, rowptr, csr_src,
                                            nullptr, (uint4*)hA, N, 0);
    // ---- layer 1 (hA is ALWAYS bf16 -> non-adaptive) ----
    k_gemm_mfma<0><<<(N + 63) / 64, 256, 0, stream>>>(hA, Wt1, fB, N, flag);
    k_gat_fused<<<ngrid4, 256, 0, stream>>>((const uint4*)fB, a1c, rowptr, csr_src,
                                            (const uint4*)hA, (uint4*)hB, N, 1);
    // ---- final layer ----
    k_gemm_mfma64<<<(N + 127) / 128, 256, 0, stream>>>(hB, Wt2f, fr2, N);
    k_gat_fused_fin<<<ngrid1, 256, 0, stream>>>(fr2, a2c, rowptr, csr_src, d_out, N, flag);
}

// Round 7
// 527.070 us; speedup vs baseline: 3.6461x; 1.0415x over previous
//
#include <hip/hip_runtime.h>
#include <hip/hip_bf16.h>

typedef __hip_bfloat16 bf16;
#define SLOPE 0.2f

__device__ __forceinline__ float b2f(bf16 v) { return __bfloat162float(v); }
__device__ __forceinline__ short f2b_raw(float x) {
    bf16 b = __float2bfloat16(x);
    return *reinterpret_cast<short*>(&b);
}

typedef __attribute__((ext_vector_type(8))) short bf16x8;
typedef __attribute__((ext_vector_type(16))) float f32x16;
typedef __attribute__((ext_vector_type(2))) float f32x2;

union Q16 { uint4 q[2]; unsigned u[8]; };

// ---------------- dtype detect: flag=0 -> bf16 inputs, flag=1 -> fp32 ----------------
__global__ void k_detect(const void* __restrict__ x, int* __restrict__ flag) {
    const unsigned short* u = (const unsigned short*)x;
    int tid = threadIdx.x;
    int nice = 0;
    for (int i = tid; i < 256; i += 64) {
        unsigned int bits = ((unsigned int)u[2 * i]) << 16;
        float v = __uint_as_float(bits);
        float av = fabsf(v);
        if (v == 0.0f || (av > 1e-6f && av < 100.0f)) ++nice;
    }
    for (int off = 32; off > 0; off >>= 1) nice += __shfl_down(nice, off, 64);
    if (tid == 0) *flag = (nice >= 192) ? 0 : 1;
}

// ---------------- merged weight prep: Wt0, Wt1, Wt2f, a0c, a1c, a2c in one launch --------
__global__ void k_prep(const void* __restrict__ W0, const void* __restrict__ W1,
                       const void* __restrict__ W2, const void* __restrict__ Wr2,
                       const void* __restrict__ a0, const void* __restrict__ a1,
                       const void* __restrict__ a2, bf16* __restrict__ Wt0,
                       bf16* __restrict__ Wt1, bf16* __restrict__ Wt2f,
                       bf16* __restrict__ a0c, bf16* __restrict__ a1c,
                       bf16* __restrict__ a2c, const int* __restrict__ flag) {
    int idx = blockIdx.x * blockDim.x + threadIdx.x;
    int isf = *flag;
    if (idx < 65536) {
        float v = isf ? ((const float*)W0)[idx] : b2f(((const bf16*)W0)[idx]);
        int k = idx >> 8, m = idx & 255;
        Wt0[m * 256 + k] = __float2bfloat16(v);
    } else if (idx < 131072) {
        int t = idx - 65536;
        float v = isf ? ((const float*)W1)[t] : b2f(((const bf16*)W1)[t]);
        int k = t >> 8, m = t & 255;
        Wt1[m * 256 + k] = __float2bfloat16(v);
    } else if (idx < 147456) {
        int t = idx - 131072;
        int j = t >> 8, k = t & 255;
        const void* src = (j < 32) ? W2 : Wr2;
        int jj = j & 31;
        float v = isf ? ((const float*)src)[k * 32 + jj] : b2f(((const bf16*)src)[k * 32 + jj]);
        Wt2f[t] = __float2bfloat16(v);
    } else if (idx < 147456 + 256) {
        int t = idx - 147456;
        float v = isf ? ((const float*)a0)[t] : b2f(((const bf16*)a0)[t]);
        a0c[t] = __float2bfloat16(v);
    } else if (idx < 147456 + 512) {
        int t = idx - 147456 - 256;
        float v = isf ? ((const float*)a1)[t] : b2f(((const bf16*)a1)[t]);
        a1c[t] = __float2bfloat16(v);
    } else if (idx < 147456 + 544) {
        int t = idx - 147456 - 512;
        float v = isf ? ((const float*)a2)[t] : b2f(((const bf16*)a2)[t]);
        a2c[t] = __float2bfloat16(v);
    }
}

// ---------------- CSR build ----------------
__global__ void k_hist(const int* __restrict__ dst, int* __restrict__ cnt, int E) {
    int e = blockIdx.x * blockDim.x + threadIdx.x;
    if (e < E) atomicAdd(&cnt[dst[e]], 1);
}

__global__ void k_bsum(const int* __restrict__ cnt, int* __restrict__ bsum, int n) {
    __shared__ int sh[256];
    int base = blockIdx.x * 1024 + threadIdx.x * 4;
    int s = 0;
#pragma unroll
    for (int k = 0; k < 4; ++k) { int i = base + k; if (i < n) s += cnt[i]; }
    sh[threadIdx.x] = s;
    __syncthreads();
    for (int off = 128; off > 0; off >>= 1) {
        if (threadIdx.x < off) sh[threadIdx.x] += sh[threadIdx.x + off];
        __syncthreads();
    }
    if (threadIdx.x == 0) bsum[blockIdx.x] = sh[0];
}

__global__ void k_bscan(int* __restrict__ bsum, int B) {
    __shared__ int sh[1024];
    int t = threadIdx.x;
    int v = (t < B) ? bsum[t] : 0;
    sh[t] = v;
    __syncthreads();
    for (int off = 1; off < 1024; off <<= 1) {
        int u = (t >= off) ? sh[t - off] : 0;
        __syncthreads();
        sh[t] += u;
        __syncthreads();
    }
    if (t < B) bsum[t] = sh[t] - v;
}

__global__ void k_scanwrite(const int* __restrict__ cnt, const int* __restrict__ bsum,
                            int* __restrict__ rowptr, int* __restrict__ cursor, int n, int E) {
    __shared__ int sh[256];
    int base = blockIdx.x * 1024 + threadIdx.x * 4;
    int loc[4];
    int s = 0;
#pragma unroll
    for (int k = 0; k < 4; ++k) {
        int i = base + k;
        loc[k] = (i < n) ? cnt[i] : 0;
        s += loc[k];
    }
    sh[threadIdx.x] = s;
    __syncthreads();
    for (int off = 1; off < 256; off <<= 1) {
        int u = (threadIdx.x >= off) ? sh[threadIdx.x - off] : 0;
        __syncthreads();
        sh[threadIdx.x] += u;
        __syncthreads();
    }
    int run = bsum[blockIdx.x] + sh[threadIdx.x] - s;
#pragma unroll
    for (int k = 0; k < 4; ++k) {
        int i = base + k;
        if (i < n) { rowptr[i] = run; cursor[i] = run; run += loc[k]; }
    }
    if (blockIdx.x == 0 && threadIdx.x == 0) rowptr[n] = E;
}

__global__ void k_scatter(const int* __restrict__ src, const int* __restrict__ dst,
                          int* __restrict__ cursor, int* __restrict__ csr_src, int E) {
    int e = blockIdx.x * blockDim.x + threadIdx.x;
    if (e < E) {
        int p = atomicAdd(&cursor[dst[e]], 1);
        csr_src[p] = src[e];
    }
}

// ---------------- MFMA GEMM: C[N,256](bf16) = A[N,256] @ W; Wt[n][k] pre-transposed ----
template <int ADAPT>
__global__ void k_gemm_mfma(const void* __restrict__ A, const bf16* __restrict__ Wt,
                            bf16* __restrict__ C, int Nrows, const int* __restrict__ flag) {
    int warp = threadIdx.x >> 6;
    int lane = threadIdx.x & 63;
    int wr = warp >> 1;
    int wc = warp & 1;
    long rowBase = (long)blockIdx.x * 64 + wr * 32;
    int colBase = wc * 128;
    int m = lane & 31;
    int g = lane >> 5;
    long r = rowBase + m;
    if (r >= Nrows) r = Nrows - 1;
    int isf32 = ADAPT ? *flag : 0;
    const short* Ab = (const short*)A + r * 256 + g * 8;
    const float* Af = (const float*)A + r * 256 + g * 8;
    const short* Wts = (const short*)Wt;
    f32x16 acc[4] = {};
    for (int k0 = 0; k0 < 256; k0 += 16) {
        bf16x8 af;
        if (ADAPT && isf32) {
            float4 x0 = *(const float4*)(Af + k0);
            float4 x1 = *(const float4*)(Af + k0 + 4);
            union { bf16x8 v; short s[8]; } t;
            t.s[0] = f2b_raw(x0.x); t.s[1] = f2b_raw(x0.y);
            t.s[2] = f2b_raw(x0.z); t.s[3] = f2b_raw(x0.w);
            t.s[4] = f2b_raw(x1.x); t.s[5] = f2b_raw(x1.y);
            t.s[6] = f2b_raw(x1.z); t.s[7] = f2b_raw(x1.w);
            af = t.v;
        } else {
            af = *(const bf16x8*)(Ab + k0);
        }
#pragma unroll
        for (int ct = 0; ct < 4; ++ct) {
            int n = colBase + ct * 32 + m;
            bf16x8 bfr = *(const bf16x8*)(Wts + (long)n * 256 + k0 + g * 8);
            acc[ct] = __builtin_amdgcn_mfma_f32_32x32x16_bf16(af, bfr, acc[ct], 0, 0, 0);
        }
    }
#pragma unroll
    for (int ct = 0; ct < 4; ++ct) {
#pragma unroll
        for (int i = 0; i < 16; ++i) {
            long row = rowBase + (i & 3) + 8 * (i >> 2) + 4 * g;
            if (row < Nrows)
                C[row * 256 + colBase + ct * 32 + m] = __float2bfloat16(acc[ct][i]);
        }
    }
}

// C[N,64] = A[N,256](bf16) @ (Wt2f[64][256])^T ; block 4 waves = 128 rows x 64 cols
__global__ void k_gemm_mfma64(const bf16* __restrict__ A, const bf16* __restrict__ Wt,
                              bf16* __restrict__ C, int Nrows) {
    int warp = threadIdx.x >> 6;
    int lane = threadIdx.x & 63;
    long rowBase = (long)blockIdx.x * 128 + warp * 32;
    int m = lane & 31;
    int g = lane >> 5;
    long r = rowBase + m;
    if (r >= Nrows) r = Nrows - 1;
    const short* Arow = (const short*)A + r * 256 + g * 8;
    const short* Wts = (const short*)Wt;
    f32x16 acc[2] = {};
    for (int k0 = 0; k0 < 256; k0 += 16) {
        bf16x8 af = *(const bf16x8*)(Arow + k0);
#pragma unroll
        for (int ct = 0; ct < 2; ++ct) {
            bf16x8 bfr = *(const bf16x8*)(Wts + (long)(ct * 32 + m) * 256 + k0 + g * 8);
            acc[ct] = __builtin_amdgcn_mfma_f32_32x32x16_bf16(af, bfr, acc[ct], 0, 0, 0);
        }
    }
#pragma unroll
    for (int ct = 0; ct < 2; ++ct) {
#pragma unroll
        for (int i = 0; i < 16; ++i) {
            long row = rowBase + (i & 3) + 8 * (i >> 2) + 4 * g;
            if (row < Nrows)
                C[row * 64 + ct * 32 + m] = __float2bfloat16(acc[ct][i]);
        }
    }
}

// ---------------- Fused GATv2 layer: 4 edges/iter, 16 lanes/edge, 16 dims/lane ----------
// lrelu(u) = 0.6u + 0.4|u|  ->  t = sum (0.6a)*u + (0.4a)*|u|, packed f32x2 math.
__global__ void k_gat_fused(const uint4* __restrict__ f, const bf16* __restrict__ a,
                            const int* __restrict__ rowptr, const int* __restrict__ csr_src,
                            const uint4* __restrict__ res, uint4* __restrict__ out,
                            int N, int mode) {
    int n = (blockIdx.x * blockDim.x + threadIdx.x) >> 6;
    int lane = threadIdx.x & 63;
    if (n >= N) return;
    int j = lane >> 4, l = lane & 15;

    Q16 fdq, aq;
    fdq.q[0] = f[(long)n * 32 + 2 * l];
    fdq.q[1] = f[(long)n * 32 + 2 * l + 1];
    aq.q[0] = ((const uint4*)a)[2 * l];
    aq.q[1] = ((const uint4*)a)[2 * l + 1];
    f32x2 fd2[8], a6[8], a4[8];
#pragma unroll
    for (int i = 0; i < 8; ++i) {
        f32x2 fv, av;
        fv.x = __uint_as_float(fdq.u[i] << 16);
        fv.y = __uint_as_float(fdq.u[i] & 0xffff0000u);
        av.x = __uint_as_float(aq.u[i] << 16);
        av.y = __uint_as_float(aq.u[i] & 0xffff0000u);
        fd2[i] = fv;
        a6[i] = 0.6f * av;
        a4[i] = 0.4f * av;
    }

    int p0 = rowptr[n], p1 = rowptr[n + 1];
    int iters = (p1 - p0 + 3) >> 2;
    float z = 0.f;
    f32x2 acc[8] = {};

    int p = p0 + j;
    Q16 cur, nxt;
    {
        int s = csr_src[min(p, p1 - 1)];
        cur.q[0] = f[(long)s * 32 + 2 * l];
        cur.q[1] = f[(long)s * 32 + 2 * l + 1];
    }
    for (int i = 0; i < iters; ++i) {
        if (i + 1 < iters) {
            int s = csr_src[min(p + 4, p1 - 1)];
            nxt.q[0] = f[(long)s * 32 + 2 * l];
            nxt.q[1] = f[(long)s * 32 + 2 * l + 1];
        }
        f32x2 fs[8];
        f32x2 t2 = {0.f, 0.f};
#pragma unroll
        for (int k = 0; k < 8; ++k) {
            f32x2 fv;
            fv.x = __uint_as_float(cur.u[k] << 16);
            fv.y = __uint_as_float(cur.u[k] & 0xffff0000u);
            fs[k] = fv;
            f32x2 u = fv + fd2[k];
            f32x2 ua;
            ua.x = __uint_as_float(__float_as_uint(u.x) & 0x7fffffffu);
            ua.y = __uint_as_float(__float_as_uint(u.y) & 0x7fffffffu);
            t2 = a6[k] * u + t2;
            t2 = a4[k] * ua + t2;
        }
        float t = t2.x + t2.y;
        t += __shfl_xor(t, 1);
        t += __shfl_xor(t, 2);
        float wgt = (p < p1) ? __expf(t) : 0.f;
        z += wgt;
        f32x2 w2 = {wgt, wgt};
#pragma unroll
        for (int k = 0; k < 8; ++k) acc[k] = w2 * fs[k] + acc[k];
        cur = nxt;
        p += 4;
    }
    // combine the 4 edge-groups
    z += __shfl_xor(z, 16);
    z += __shfl_xor(z, 32);
#pragma unroll
    for (int k = 0; k < 8; ++k) {
        acc[k].x += __shfl_xor(acc[k].x, 16);
        acc[k].x += __shfl_xor(acc[k].x, 32);
        acc[k].y += __shfl_xor(acc[k].y, 16);
        acc[k].y += __shfl_xor(acc[k].y, 32);
    }
    if (j == 0) {
        float invz = 1.f / z;
        float o[16];
        if (mode == 1) {
            Q16 rq;
            rq.q[0] = res[(long)n * 32 + 2 * l];
            rq.q[1] = res[(long)n * 32 + 2 * l + 1];
#pragma unroll
            for (int k = 0; k < 8; ++k) {
                float rx = __uint_as_float(rq.u[k] << 16);
                float ry = __uint_as_float(rq.u[k] & 0xffff0000u);
                o[2 * k]     = fmaf(acc[k].x, invz, rx);
                o[2 * k + 1] = fmaf(acc[k].y, invz, ry);
            }
        } else {
#pragma unroll
            for (int k = 0; k < 8; ++k) {
                o[2 * k]     = acc[k].x * invz;
                o[2 * k + 1] = acc[k].y * invz;
            }
        }
        union { uint4 q[2]; short s[16]; } ob;
#pragma unroll
        for (int k = 0; k < 16; ++k) {
            float v = o[k] > 0.f ? o[k] : (__expf(o[k]) - 1.f);
            ob.s[k] = f2b_raw(v);
        }
        out[(long)n * 32 + 2 * l] = ob.q[0];
        out[(long)n * 32 + 2 * l + 1] = ob.q[1];
    }
}

// ---------------- Fused final layer: fr2[N][64] = [f2 | r2]; half-wave per node ----------------
__global__ void k_gat_fused_fin(const bf16* __restrict__ fr2, const bf16* __restrict__ a2,
                                const int* __restrict__ rowptr, const int* __restrict__ csr_src,
                                void* __restrict__ outraw, int N, const int* __restrict__ flag) {
    int gid = blockIdx.x * blockDim.x + threadIdx.x;
    int n = gid >> 5;
    int il = threadIdx.x & 31;
    if (n >= N) return;
    float fd = b2f(fr2[(long)n * 64 + il]);
    float rv = b2f(fr2[(long)n * 64 + 32 + il]);
    float a2v = b2f(a2[il]);
    int p0 = rowptr[n], p1 = rowptr[n + 1];
    float z = 0.f, acc = 0.f;
    float fs = b2f(fr2[(long)csr_src[p0] * 64 + il]);
    for (int p = p0; p < p1; ++p) {
        float fsn = 0.f;
        if (p + 1 < p1) fsn = b2f(fr2[(long)csr_src[p + 1] * 64 + il]);
        float u = fs + fd;
        u = u > 0.f ? u : SLOPE * u;
        float t = u * a2v;
        t += __shfl_xor(t, 1, 32);
        t += __shfl_xor(t, 2, 32);
        t += __shfl_xor(t, 4, 32);
        t += __shfl_xor(t, 8, 32);
        t += __shfl_xor(t, 16, 32);
        float wgt = __expf(t);
        z += wgt;
        acc += wgt * fs;
        fs = fsn;
    }
    float o = acc / z + rv;
    if (*flag) ((float*)outraw)[(long)n * 32 + il] = o;
    else       ((bf16*)outraw)[(long)n * 32 + il] = __float2bfloat16(o);
}

extern "C" void kernel_launch(void* const* d_in, const int* in_sizes, int n_in,
                              void* d_out, int out_size, void* d_ws, size_t ws_size,
                              hipStream_t stream) {
    const int N = in_sizes[0] / 256;
    const int E = in_sizes[1];

    const void* x   = d_in[0];
    const int*  src = (const int*)d_in[1];
    const int*  dst = (const int*)d_in[2];

    // ---- workspace carve ----
    char* w = (char*)d_ws;
    auto alloc = [&](size_t bytes) -> char* {
        char* p = w;
        w += (bytes + 15) & ~(size_t)15;
        return p;
    };
    bf16* buf0 = (bf16*)alloc((size_t)N * 256 * 2);  // hB
    bf16* buf1 = (bf16*)alloc((size_t)N * 256 * 2);  // hA
    bf16* buf2 = (bf16*)alloc((size_t)N * 256 * 2);  // fB / fr2
    int* csr_src = (int*)alloc((size_t)E * 4);
    int* rowptr  = (int*)alloc((size_t)(N + 1) * 4);
    int* cursor  = (int*)alloc((size_t)N * 4);
    int* cnt     = (int*)alloc((size_t)N * 4);
    int* bsum    = (int*)alloc((size_t)1024 * 4);
    bf16* Wt0  = (bf16*)alloc((size_t)65536 * 2);
    bf16* Wt1  = (bf16*)alloc((size_t)65536 * 2);
    bf16* Wt2f = (bf16*)alloc((size_t)64 * 256 * 2);
    bf16* a0c  = (bf16*)alloc((size_t)256 * 2);
    bf16* a1c  = (bf16*)alloc((size_t)256 * 2);
    bf16* a2c  = (bf16*)alloc((size_t)32 * 2);
    int*  flag = (int*)alloc(16);

    bf16* hA  = buf1;
    bf16* fB  = buf2;
    bf16* hB  = buf0;
    bf16* fr2 = buf2;

    // ---- dtype detect + merged weight prep ----
    k_detect<<<1, 64, 0, stream>>>(x, flag);
    k_prep<<<(147456 + 544 + 255) / 256, 256, 0, stream>>>(
        d_in[3], d_in[5], d_in[7], d_in[9], d_in[4], d_in[6], d_in[8],
        Wt0, Wt1, Wt2f, a0c, a1c, a2c, flag);

    // ---- CSR build ----
    const int B = (N + 1023) / 1024;
    hipMemsetAsync(cnt, 0, (size_t)N * 4, stream);
    k_hist<<<(E + 255) / 256, 256, 0, stream>>>(dst, cnt, E);
    k_bsum<<<B, 256, 0, stream>>>(cnt, bsum, N);
    k_bscan<<<1, 1024, 0, stream>>>(bsum, B);
    k_scanwrite<<<B, 256, 0, stream>>>(cnt, bsum, rowptr, cursor, N, E);
    k_scatter<<<(E + 255) / 256, 256, 0, stream>>>(src, dst, cursor, csr_src, E);

    const int ngrid4 = (int)(((long)N * 64 + 255) / 256);
    const int ngrid1 = (int)(((long)N * 32 + 255) / 256);

    // ---- layer 0 (x read directly, fp32 converted in-flight) ----
    k_gemm_mfma<1><<<(N + 63) / 64, 256, 0, stream>>>(x, Wt0, fB, N, flag);
    k_gat_fused<<<ngrid4, 256, 0, stream>>>((const uint4*)fB, a0c, rowptr, csr_src,
                                            nullptr, (uint4*)hA, N, 0);
    // ---- layer 1 (hA is ALWAYS bf16 -> non-adaptive) ----
    k_gemm_mfma<0><<<(N + 63) / 64, 256, 0, stream>>>(hA, Wt1, fB, N, flag);
    k_gat_fused<<<ngrid4, 256, 0, stream>>>((const uint4*)fB, a1c, rowptr, csr_src,
                                            (const uint4*)hA, (uint4*)hB, N, 1);
    // ---- final layer ----
    k_gemm_mfma64<<<(N + 127) / 128, 256, 0, stream>>>(hB, Wt2f, fr2, N);
    k_gat_fused_fin<<<ngrid1, 256, 0, stream>>>(fr2, a2c, rowptr, csr_src, d_out, N, flag);
}

// Round 8
// 468.267 us; speedup vs baseline: 4.1040x; 1.1256x over previous
//
#include <hip/hip_runtime.h>
#include <hip/hip_bf16.h>

typedef __hip_bfloat16 bf16;
#define SLOPE 0.2f

__device__ __forceinline__ float b2f(bf16 v) { return __bfloat162float(v); }
__device__ __forceinline__ short f2b_raw(float x) {
    bf16 b = __float2bfloat16(x);
    return *reinterpret_cast<short*>(&b);
}

typedef __attribute__((ext_vector_type(8))) short bf16x8;
typedef __attribute__((ext_vector_type(16))) float f32x16;
typedef __attribute__((ext_vector_type(2))) float f32x2;

union Q16 { uint4 q[2]; unsigned u[8]; };

// ---------------- dtype detect: flag=0 -> bf16 inputs, flag=1 -> fp32 ----------------
__global__ void k_detect(const void* __restrict__ x, int* __restrict__ flag) {
    const unsigned short* u = (const unsigned short*)x;
    int tid = threadIdx.x;
    int nice = 0;
    for (int i = tid; i < 256; i += 64) {
        unsigned int bits = ((unsigned int)u[2 * i]) << 16;
        float v = __uint_as_float(bits);
        float av = fabsf(v);
        if (v == 0.0f || (av > 1e-6f && av < 100.0f)) ++nice;
    }
    for (int off = 32; off > 0; off >>= 1) nice += __shfl_down(nice, off, 64);
    if (tid == 0) *flag = (nice >= 192) ? 0 : 1;
}

// ---------------- merged weight prep. W0p/W1p/W2fp are packed in MFMA B-fragment order:
// idx = (((nt*16 + kt)*64 + lane)*8 + j); value = W[k*M + n], n = nt*32+(lane&31),
// k = kt*16 + (lane>>5)*8 + j.  -> GEMM B loads become lane-contiguous 16B streams.
__global__ void k_prep(const void* __restrict__ W0, const void* __restrict__ W1,
                       const void* __restrict__ W2, const void* __restrict__ Wr2,
                       const void* __restrict__ a0, const void* __restrict__ a1,
                       const void* __restrict__ a2, bf16* __restrict__ W0p,
                       bf16* __restrict__ W1p, bf16* __restrict__ W2fp,
                       bf16* __restrict__ a0c, bf16* __restrict__ a1c,
                       bf16* __restrict__ a2c, const int* __restrict__ flag) {
    int idx = blockIdx.x * blockDim.x + threadIdx.x;
    int isf = *flag;
    if (idx < 131072) {  // W0p (first 65536) and W1p
        int t = idx & 65535;
        int j = t & 7, L = (t >> 3) & 63, kt = (t >> 9) & 15, nt = t >> 13;
        int n = nt * 32 + (L & 31);
        int k = kt * 16 + (L >> 5) * 8 + j;
        const void* src = (idx < 65536) ? W0 : W1;
        float v = isf ? ((const float*)src)[k * 256 + n] : b2f(((const bf16*)src)[k * 256 + n]);
        bf16* dstp = (idx < 65536) ? W0p : W1p;
        dstp[t] = __float2bfloat16(v);
    } else if (idx < 147456) {  // W2fp: 64 cols = [W2 | Wres2], 16384 elems
        int t = idx - 131072;
        int j = t & 7, L = (t >> 3) & 63, kt = (t >> 9) & 15, nt = t >> 13;
        int n = nt * 32 + (L & 31);
        int k = kt * 16 + (L >> 5) * 8 + j;
        const void* src = (n < 32) ? W2 : Wr2;
        int nn = n & 31;
        float v = isf ? ((const float*)src)[k * 32 + nn] : b2f(((const bf16*)src)[k * 32 + nn]);
        W2fp[t] = __float2bfloat16(v);
    } else if (idx < 147456 + 256) {
        int t = idx - 147456;
        float v = isf ? ((const float*)a0)[t] : b2f(((const bf16*)a0)[t]);
        a0c[t] = __float2bfloat16(v);
    } else if (idx < 147456 + 512) {
        int t = idx - 147456 - 256;
        float v = isf ? ((const float*)a1)[t] : b2f(((const bf16*)a1)[t]);
        a1c[t] = __float2bfloat16(v);
    } else if (idx < 147456 + 544) {
        int t = idx - 147456 - 512;
        float v = isf ? ((const float*)a2)[t] : b2f(((const bf16*)a2)[t]);
        a2c[t] = __float2bfloat16(v);
    }
}

// ---------------- CSR build ----------------
__global__ void k_hist(const int* __restrict__ dst, int* __restrict__ cnt, int E) {
    int e = blockIdx.x * blockDim.x + threadIdx.x;
    if (e < E) atomicAdd(&cnt[dst[e]], 1);
}

__global__ void k_bsum(const int* __restrict__ cnt, int* __restrict__ bsum, int n) {
    __shared__ int sh[256];
    int base = blockIdx.x * 1024 + threadIdx.x * 4;
    int s = 0;
#pragma unroll
    for (int k = 0; k < 4; ++k) { int i = base + k; if (i < n) s += cnt[i]; }
    sh[threadIdx.x] = s;
    __syncthreads();
    for (int off = 128; off > 0; off >>= 1) {
        if (threadIdx.x < off) sh[threadIdx.x] += sh[threadIdx.x + off];
        __syncthreads();
    }
    if (threadIdx.x == 0) bsum[blockIdx.x] = sh[0];
}

__global__ void k_bscan(int* __restrict__ bsum, int B) {
    __shared__ int sh[1024];
    int t = threadIdx.x;
    int v = (t < B) ? bsum[t] : 0;
    sh[t] = v;
    __syncthreads();
    for (int off = 1; off < 1024; off <<= 1) {
        int u = (t >= off) ? sh[t - off] : 0;
        __syncthreads();
        sh[t] += u;
        __syncthreads();
    }
    if (t < B) bsum[t] = sh[t] - v;
}

__global__ void k_scanwrite(const int* __restrict__ cnt, const int* __restrict__ bsum,
                            int* __restrict__ rowptr, int* __restrict__ cursor, int n, int E) {
    __shared__ int sh[256];
    int base = blockIdx.x * 1024 + threadIdx.x * 4;
    int loc[4];
    int s = 0;
#pragma unroll
    for (int k = 0; k < 4; ++k) {
        int i = base + k;
        loc[k] = (i < n) ? cnt[i] : 0;
        s += loc[k];
    }
    sh[threadIdx.x] = s;
    __syncthreads();
    for (int off = 1; off < 256; off <<= 1) {
        int u = (threadIdx.x >= off) ? sh[threadIdx.x - off] : 0;
        __syncthreads();
        sh[threadIdx.x] += u;
        __syncthreads();
    }
    int run = bsum[blockIdx.x] + sh[threadIdx.x] - s;
#pragma unroll
    for (int k = 0; k < 4; ++k) {
        int i = base + k;
        if (i < n) { rowptr[i] = run; cursor[i] = run; run += loc[k]; }
    }
    if (blockIdx.x == 0 && threadIdx.x == 0) rowptr[n] = E;
}

__global__ void k_scatter(const int* __restrict__ src, const int* __restrict__ dst,
                          int* __restrict__ cursor, int* __restrict__ csr_src, int E) {
    int e = blockIdx.x * blockDim.x + threadIdx.x;
    if (e < E) {
        int p = atomicAdd(&cursor[dst[e]], 1);
        csr_src[p] = src[e];
    }
}

// ---------------- MFMA GEMM: C[N,256](bf16) = A[N,256] @ W; B pre-packed fragments ----
template <int ADAPT>
__global__ void k_gemm_mfma(const void* __restrict__ A, const bf16* __restrict__ Wp,
                            bf16* __restrict__ C, int Nrows, const int* __restrict__ flag) {
    int warp = threadIdx.x >> 6;
    int lane = threadIdx.x & 63;
    int wr = warp >> 1;
    int wc = warp & 1;
    long rowBase = (long)blockIdx.x * 64 + wr * 32;
    int colBase = wc * 128;
    int m = lane & 31;
    int g = lane >> 5;
    long r = rowBase + m;
    if (r >= Nrows) r = Nrows - 1;
    int isf32 = ADAPT ? *flag : 0;
    const short* Ab = (const short*)A + r * 256 + g * 8;
    const float* Af = (const float*)A + r * 256 + g * 8;
    const short* Wps = (const short*)Wp;
    f32x16 acc[4] = {};
    for (int kt = 0; kt < 16; ++kt) {
        bf16x8 af;
        if (ADAPT && isf32) {
            float4 x0 = *(const float4*)(Af + kt * 16);
            float4 x1 = *(const float4*)(Af + kt * 16 + 4);
            union { bf16x8 v; short s[8]; } t;
            t.s[0] = f2b_raw(x0.x); t.s[1] = f2b_raw(x0.y);
            t.s[2] = f2b_raw(x0.z); t.s[3] = f2b_raw(x0.w);
            t.s[4] = f2b_raw(x1.x); t.s[5] = f2b_raw(x1.y);
            t.s[6] = f2b_raw(x1.z); t.s[7] = f2b_raw(x1.w);
            af = t.v;
        } else {
            af = *(const bf16x8*)(Ab + kt * 16);
        }
#pragma unroll
        for (int ct = 0; ct < 4; ++ct) {
            int nt = wc * 4 + ct;
            bf16x8 bfr = *(const bf16x8*)(Wps + (((nt << 4) + kt) << 9) + lane * 8);
            acc[ct] = __builtin_amdgcn_mfma_f32_32x32x16_bf16(af, bfr, acc[ct], 0, 0, 0);
        }
    }
#pragma unroll
    for (int ct = 0; ct < 4; ++ct) {
#pragma unroll
        for (int i = 0; i < 16; ++i) {
            long row = rowBase + (i & 3) + 8 * (i >> 2) + 4 * g;
            if (row < Nrows)
                C[row * 256 + colBase + ct * 32 + m] = __float2bfloat16(acc[ct][i]);
        }
    }
}

// C[N,64] = A[N,256](bf16) @ combined final weights (fragment-packed)
__global__ void k_gemm_mfma64(const bf16* __restrict__ A, const bf16* __restrict__ Wp,
                              bf16* __restrict__ C, int Nrows) {
    int warp = threadIdx.x >> 6;
    int lane = threadIdx.x & 63;
    long rowBase = (long)blockIdx.x * 128 + warp * 32;
    int m = lane & 31;
    int g = lane >> 5;
    long r = rowBase + m;
    if (r >= Nrows) r = Nrows - 1;
    const short* Arow = (const short*)A + r * 256 + g * 8;
    const short* Wps = (const short*)Wp;
    f32x16 acc[2] = {};
    for (int kt = 0; kt < 16; ++kt) {
        bf16x8 af = *(const bf16x8*)(Arow + kt * 16);
#pragma unroll
        for (int ct = 0; ct < 2; ++ct) {
            bf16x8 bfr = *(const bf16x8*)(Wps + (((ct << 4) + kt) << 9) + lane * 8);
            acc[ct] = __builtin_amdgcn_mfma_f32_32x32x16_bf16(af, bfr, acc[ct], 0, 0, 0);
        }
    }
#pragma unroll
    for (int ct = 0; ct < 2; ++ct) {
#pragma unroll
        for (int i = 0; i < 16; ++i) {
            long row = rowBase + (i & 3) + 8 * (i >> 2) + 4 * g;
            if (row < Nrows)
                C[row * 64 + ct * 32 + m] = __float2bfloat16(acc[ct][i]);
        }
    }
}

// ---------------- Fused GATv2 layer: 8 edges/iter (2 per slot), 16 lanes/edge ----------
// lrelu(u) = 0.6u + 0.4|u|  ->  t = sum (0.6a)*u + (0.4a)*|u|, packed f32x2 math.
__global__ void k_gat_fused(const uint4* __restrict__ f, const bf16* __restrict__ a,
                            const int* __restrict__ rowptr, const int* __restrict__ csr_src,
                            const uint4* __restrict__ res, uint4* __restrict__ out,
                            int N, int mode) {
    int n = (blockIdx.x * blockDim.x + threadIdx.x) >> 6;
    int lane = threadIdx.x & 63;
    if (n >= N) return;
    int j = lane >> 4, l = lane & 15;

    Q16 fdq, aq;
    fdq.q[0] = f[(long)n * 32 + 2 * l];
    fdq.q[1] = f[(long)n * 32 + 2 * l + 1];
    aq.q[0] = ((const uint4*)a)[2 * l];
    aq.q[1] = ((const uint4*)a)[2 * l + 1];
    f32x2 fd2[8], a6[8], a4[8];
#pragma unroll
    for (int i = 0; i < 8; ++i) {
        f32x2 fv, av;
        fv.x = __uint_as_float(fdq.u[i] << 16);
        fv.y = __uint_as_float(fdq.u[i] & 0xffff0000u);
        av.x = __uint_as_float(aq.u[i] << 16);
        av.y = __uint_as_float(aq.u[i] & 0xffff0000u);
        fd2[i] = fv;
        a6[i] = 0.6f * av;
        a4[i] = 0.4f * av;
    }

    int p0 = rowptr[n], p1 = rowptr[n + 1];
    int iters = (p1 - p0 + 3) >> 2;  // per-slot serial count
    float z = 0.f;
    f32x2 acc[8] = {};

    int p = p0 + j;
    int pc = p1 - 1;
    Q16 A0, A1, B0, B1;
    {
        int s0 = csr_src[min(p, pc)];
        A0.q[0] = f[(long)s0 * 32 + 2 * l];
        A0.q[1] = f[(long)s0 * 32 + 2 * l + 1];
        int s1 = csr_src[min(p + 4, pc)];
        A1.q[0] = f[(long)s1 * 32 + 2 * l];
        A1.q[1] = f[(long)s1 * 32 + 2 * l + 1];
    }
    for (int i = 0; i < iters; i += 2) {
        // prefetch next pair of rows for this slot
        int s0 = csr_src[min(p + 8, pc)];
        B0.q[0] = f[(long)s0 * 32 + 2 * l];
        B0.q[1] = f[(long)s0 * 32 + 2 * l + 1];
        int s1 = csr_src[min(p + 12, pc)];
        B1.q[0] = f[(long)s1 * 32 + 2 * l];
        B1.q[1] = f[(long)s1 * 32 + 2 * l + 1];

#pragma unroll
        for (int half = 0; half < 2; ++half) {
            if (half == 1 && i + 1 >= iters) break;
            const Q16& cur = half ? A1 : A0;
            int pp = p + half * 4;
            f32x2 fs[8];
            f32x2 t2 = {0.f, 0.f};
#pragma unroll
            for (int k = 0; k < 8; ++k) {
                f32x2 fv;
                fv.x = __uint_as_float(cur.u[k] << 16);
                fv.y = __uint_as_float(cur.u[k] & 0xffff0000u);
                fs[k] = fv;
                f32x2 u = fv + fd2[k];
                f32x2 ua;
                ua.x = __uint_as_float(__float_as_uint(u.x) & 0x7fffffffu);
                ua.y = __uint_as_float(__float_as_uint(u.y) & 0x7fffffffu);
                t2 = a6[k] * u + t2;
                t2 = a4[k] * ua + t2;
            }
            float t = t2.x + t2.y;
            t += __shfl_xor(t, 1);
            t += __shfl_xor(t, 2);
            float wgt = (pp < p1) ? __expf(t) : 0.f;
            z += wgt;
            f32x2 w2 = {wgt, wgt};
#pragma unroll
            for (int k = 0; k < 8; ++k) acc[k] = w2 * fs[k] + acc[k];
        }
        A0 = B0;
        A1 = B1;
        p += 8;
    }
    // combine the 4 edge-groups
    z += __shfl_xor(z, 16);
    z += __shfl_xor(z, 32);
#pragma unroll
    for (int k = 0; k < 8; ++k) {
        acc[k].x += __shfl_xor(acc[k].x, 16);
        acc[k].x += __shfl_xor(acc[k].x, 32);
        acc[k].y += __shfl_xor(acc[k].y, 16);
        acc[k].y += __shfl_xor(acc[k].y, 32);
    }
    // epilogue split across groups j=0 (elems 0..7) and j=1 (elems 8..15)
    if (j < 2) {
        float invz = 1.f / z;
        float o[8];
#pragma unroll
        for (int k = 0; k < 4; ++k) {
            int kk = j * 4 + k;
            o[2 * k]     = acc[kk].x * invz;
            o[2 * k + 1] = acc[kk].y * invz;
        }
        if (mode == 1) {
            uint4 rq = res[(long)n * 32 + 2 * l + j];
            const unsigned* ru = (const unsigned*)&rq;
#pragma unroll
            for (int k = 0; k < 4; ++k) {
                o[2 * k]     += __uint_as_float(ru[k] << 16);
                o[2 * k + 1] += __uint_as_float(ru[k] & 0xffff0000u);
            }
        }
        union { uint4 q; short s[8]; } ob;
#pragma unroll
        for (int k = 0; k < 8; ++k) {
            float v = o[k] > 0.f ? o[k] : (__expf(o[k]) - 1.f);
            ob.s[k] = f2b_raw(v);
        }
        out[(long)n * 32 + 2 * l + j] = ob.q;
    }
}

// ---------------- Fused final layer: fr2[N][64] = [f2 | r2]; half-wave per node ----------------
__global__ void k_gat_fused_fin(const bf16* __restrict__ fr2, const bf16* __restrict__ a2,
                                const int* __restrict__ rowptr, const int* __restrict__ csr_src,
                                void* __restrict__ outraw, int N, const int* __restrict__ flag) {
    int gid = blockIdx.x * blockDim.x + threadIdx.x;
    int n = gid >> 5;
    int il = threadIdx.x & 31;
    if (n >= N) return;
    float fd = b2f(fr2[(long)n * 64 + il]);
    float rv = b2f(fr2[(long)n * 64 + 32 + il]);
    float a2v = b2f(a2[il]);
    int p0 = rowptr[n], p1 = rowptr[n + 1];
    float z = 0.f, acc = 0.f;
    float fs = b2f(fr2[(long)csr_src[p0] * 64 + il]);
    for (int p = p0; p < p1; ++p) {
        float fsn = 0.f;
        if (p + 1 < p1) fsn = b2f(fr2[(long)csr_src[p + 1] * 64 + il]);
        float u = fs + fd;
        u = u > 0.f ? u : SLOPE * u;
        float t = u * a2v;
        t += __shfl_xor(t, 1, 32);
        t += __shfl_xor(t, 2, 32);
        t += __shfl_xor(t, 4, 32);
        t += __shfl_xor(t, 8, 32);
        t += __shfl_xor(t, 16, 32);
        float wgt = __expf(t);
        z += wgt;
        acc += wgt * fs;
        fs = fsn;
    }
    float o = acc / z + rv;
    if (*flag) ((float*)outraw)[(long)n * 32 + il] = o;
    else       ((bf16*)outraw)[(long)n * 32 + il] = __float2bfloat16(o);
}

extern "C" void kernel_launch(void* const* d_in, const int* in_sizes, int n_in,
                              void* d_out, int out_size, void* d_ws, size_t ws_size,
                              hipStream_t stream) {
    const int N = in_sizes[0] / 256;
    const int E = in_sizes[1];

    const void* x   = d_in[0];
    const int*  src = (const int*)d_in[1];
    const int*  dst = (const int*)d_in[2];

    // ---- workspace carve ----
    char* w = (char*)d_ws;
    auto alloc = [&](size_t bytes) -> char* {
        char* p = w;
        w += (bytes + 15) & ~(size_t)15;
        return p;
    };
    bf16* buf0 = (bf16*)alloc((size_t)N * 256 * 2);  // hB
    bf16* buf1 = (bf16*)alloc((size_t)N * 256 * 2);  // hA
    bf16* buf2 = (bf16*)alloc((size_t)N * 256 * 2);  // fB / fr2
    int* csr_src = (int*)alloc((size_t)E * 4);
    int* rowptr  = (int*)alloc((size_t)(N + 1) * 4);
    int* cursor  = (int*)alloc((size_t)N * 4);
    int* cnt     = (int*)alloc((size_t)N * 4);
    int* bsum    = (int*)alloc((size_t)1024 * 4);
    bf16* W0p  = (bf16*)alloc((size_t)65536 * 2);
    bf16* W1p  = (bf16*)alloc((size_t)65536 * 2);
    bf16* W2fp = (bf16*)alloc((size_t)64 * 256 * 2);
    bf16* a0c  = (bf16*)alloc((size_t)256 * 2);
    bf16* a1c  = (bf16*)alloc((size_t)256 * 2);
    bf16* a2c  = (bf16*)alloc((size_t)32 * 2);
    int*  flag = (int*)alloc(16);

    bf16* hA  = buf1;
    bf16* fB  = buf2;
    bf16* hB  = buf0;
    bf16* fr2 = buf2;

    // ---- dtype detect + merged weight prep ----
    k_detect<<<1, 64, 0, stream>>>(x, flag);
    k_prep<<<(147456 + 544 + 255) / 256, 256, 0, stream>>>(
        d_in[3], d_in[5], d_in[7], d_in[9], d_in[4], d_in[6], d_in[8],
        W0p, W1p, W2fp, a0c, a1c, a2c, flag);

    // ---- CSR build ----
    const int B = (N + 1023) / 1024;
    hipMemsetAsync(cnt, 0, (size_t)N * 4, stream);
    k_hist<<<(E + 255) / 256, 256, 0, stream>>>(dst, cnt, E);
    k_bsum<<<B, 256, 0, stream>>>(cnt, bsum, N);
    k_bscan<<<1, 1024, 0, stream>>>(bsum, B);
    k_scanwrite<<<B, 256, 0, stream>>>(cnt, bsum, rowptr, cursor, N, E);
    k_scatter<<<(E + 255) / 256, 256, 0, stream>>>(src, dst, cursor, csr_src, E);

    const int ngrid4 = (int)(((long)N * 64 + 255) / 256);
    const int ngrid1 = (int)(((long)N * 32 + 255) / 256);

    // ---- layer 0 (x read directly, fp32 converted in-flight) ----
    k_gemm_mfma<1><<<(N + 63) / 64, 256, 0, stream>>>(x, W0p, fB, N, flag);
    k_gat_fused<<<ngrid4, 256, 0, stream>>>((const uint4*)fB, a0c, rowptr, csr_src,
                                            nullptr, (uint4*)hA, N, 0);
    // ---- layer 1 (hA is ALWAYS bf16 -> non-adaptive) ----
    k_gemm_mfma<0><<<(N + 63) / 64, 256, 0, stream>>>(hA, W1p, fB, N, flag);
    k_gat_fused<<<ngrid4, 256, 0, stream>>>((const uint4*)fB, a1c, rowptr, csr_src,
                                            (const uint4*)hA, (uint4*)hB, N, 1);
    // ---- final layer ----
    k_gemm_mfma64<<<(N + 127) / 128, 256, 0, stream>>>(hB, W2fp, fr2, N);
    k_gat_fused_fin<<<ngrid1, 256, 0, stream>>>(fr2, a2c, rowptr, csr_src, d_out, N, flag);
}

// Round 9
// 442.704 us; speedup vs baseline: 4.3409x; 1.0577x over previous
//
#include <hip/hip_runtime.h>
#include <hip/hip_bf16.h>

typedef __hip_bfloat16 bf16;
#define SLOPE 0.2f

__device__ __forceinline__ float b2f(bf16 v) { return __bfloat162float(v); }
__device__ __forceinline__ short f2b_raw(float x) {
    bf16 b = __float2bfloat16(x);
    return *reinterpret_cast<short*>(&b);
}

typedef __attribute__((ext_vector_type(8))) short bf16x8;
typedef __attribute__((ext_vector_type(16))) float f32x16;
typedef __attribute__((ext_vector_type(2))) float f32x2;

union Q16 { uint4 q[2]; unsigned u[8]; };

// ---------------- dtype detect (block 0) + cnt zeroing (all blocks) ----------------
__global__ void k_detect(const void* __restrict__ x, int* __restrict__ flag,
                         int* __restrict__ cnt, int n) {
    int i = blockIdx.x * blockDim.x + threadIdx.x;
    if (i < n) cnt[i] = 0;
    if (blockIdx.x == 0 && threadIdx.x < 64) {
        const unsigned short* u = (const unsigned short*)x;
        int tid = threadIdx.x;
        int nice = 0;
        for (int k = tid; k < 256; k += 64) {
            unsigned int bits = ((unsigned int)u[2 * k]) << 16;
            float v = __uint_as_float(bits);
            float av = fabsf(v);
            if (v == 0.0f || (av > 1e-6f && av < 100.0f)) ++nice;
        }
        for (int off = 32; off > 0; off >>= 1) nice += __shfl_down(nice, off, 64);
        if (tid == 0) *flag = (nice >= 192) ? 0 : 1;
    }
}

// ---------------- merged weight prep. W0p/W1p/W2fp packed in MFMA B-fragment order ----
__global__ void k_prep(const void* __restrict__ W0, const void* __restrict__ W1,
                       const void* __restrict__ W2, const void* __restrict__ Wr2,
                       const void* __restrict__ a0, const void* __restrict__ a1,
                       const void* __restrict__ a2, bf16* __restrict__ W0p,
                       bf16* __restrict__ W1p, bf16* __restrict__ W2fp,
                       bf16* __restrict__ a0c, bf16* __restrict__ a1c,
                       bf16* __restrict__ a2c, const int* __restrict__ flag) {
    int idx = blockIdx.x * blockDim.x + threadIdx.x;
    int isf = *flag;
    if (idx < 131072) {
        int t = idx & 65535;
        int j = t & 7, L = (t >> 3) & 63, kt = (t >> 9) & 15, nt = t >> 13;
        int n = nt * 32 + (L & 31);
        int k = kt * 16 + (L >> 5) * 8 + j;
        const void* src = (idx < 65536) ? W0 : W1;
        float v = isf ? ((const float*)src)[k * 256 + n] : b2f(((const bf16*)src)[k * 256 + n]);
        bf16* dstp = (idx < 65536) ? W0p : W1p;
        dstp[t] = __float2bfloat16(v);
    } else if (idx < 147456) {
        int t = idx - 131072;
        int j = t & 7, L = (t >> 3) & 63, kt = (t >> 9) & 15, nt = t >> 13;
        int n = nt * 32 + (L & 31);
        int k = kt * 16 + (L >> 5) * 8 + j;
        const void* src = (n < 32) ? W2 : Wr2;
        int nn = n & 31;
        float v = isf ? ((const float*)src)[k * 32 + nn] : b2f(((const bf16*)src)[k * 32 + nn]);
        W2fp[t] = __float2bfloat16(v);
    } else if (idx < 147456 + 256) {
        int t = idx - 147456;
        float v = isf ? ((const float*)a0)[t] : b2f(((const bf16*)a0)[t]);
        a0c[t] = __float2bfloat16(v);
    } else if (idx < 147456 + 512) {
        int t = idx - 147456 - 256;
        float v = isf ? ((const float*)a1)[t] : b2f(((const bf16*)a1)[t]);
        a1c[t] = __float2bfloat16(v);
    } else if (idx < 147456 + 544) {
        int t = idx - 147456 - 512;
        float v = isf ? ((const float*)a2)[t] : b2f(((const bf16*)a2)[t]);
        a2c[t] = __float2bfloat16(v);
    }
}

// ---------------- CSR build ----------------
__global__ void k_hist(const int* __restrict__ dst, int* __restrict__ cnt, int E) {
    int e = blockIdx.x * blockDim.x + threadIdx.x;
    if (e < E) atomicAdd(&cnt[dst[e]], 1);
}

__global__ void k_bsum(const int* __restrict__ cnt, int* __restrict__ bsum, int n) {
    __shared__ int sh[256];
    int base = blockIdx.x * 1024 + threadIdx.x * 4;
    int s = 0;
#pragma unroll
    for (int k = 0; k < 4; ++k) { int i = base + k; if (i < n) s += cnt[i]; }
    sh[threadIdx.x] = s;
    __syncthreads();
    for (int off = 128; off > 0; off >>= 1) {
        if (threadIdx.x < off) sh[threadIdx.x] += sh[threadIdx.x + off];
        __syncthreads();
    }
    if (threadIdx.x == 0) bsum[blockIdx.x] = sh[0];
}

__global__ void k_bscan(int* __restrict__ bsum, int B) {
    __shared__ int sh[1024];
    int t = threadIdx.x;
    int v = (t < B) ? bsum[t] : 0;
    sh[t] = v;
    __syncthreads();
    for (int off = 1; off < 1024; off <<= 1) {
        int u = (t >= off) ? sh[t - off] : 0;
        __syncthreads();
        sh[t] += u;
        __syncthreads();
    }
    if (t < B) bsum[t] = sh[t] - v;
}

__global__ void k_scanwrite(const int* __restrict__ cnt, const int* __restrict__ bsum,
                            int* __restrict__ rowptr, int* __restrict__ cursor, int n, int E) {
    __shared__ int sh[256];
    int base = blockIdx.x * 1024 + threadIdx.x * 4;
    int loc[4];
    int s = 0;
#pragma unroll
    for (int k = 0; k < 4; ++k) {
        int i = base + k;
        loc[k] = (i < n) ? cnt[i] : 0;
        s += loc[k];
    }
    sh[threadIdx.x] = s;
    __syncthreads();
    for (int off = 1; off < 256; off <<= 1) {
        int u = (threadIdx.x >= off) ? sh[threadIdx.x - off] : 0;
        __syncthreads();
        sh[threadIdx.x] += u;
        __syncthreads();
    }
    int run = bsum[blockIdx.x] + sh[threadIdx.x] - s;
#pragma unroll
    for (int k = 0; k < 4; ++k) {
        int i = base + k;
        if (i < n) { rowptr[i] = run; cursor[i] = run; run += loc[k]; }
    }
    if (blockIdx.x == 0 && threadIdx.x == 0) rowptr[n] = E;
}

__global__ void k_scatter(const int* __restrict__ src, const int* __restrict__ dst,
                          int* __restrict__ cursor, int* __restrict__ csr_src, int E) {
    int e = blockIdx.x * blockDim.x + threadIdx.x;
    if (e < E) {
        int p = atomicAdd(&cursor[dst[e]], 1);
        csr_src[p] = src[e];
    }
}

// ---------------- MFMA GEMM: C[N,256](bf16) = A[N,256] @ W; B pre-packed fragments ----
template <int ADAPT>
__global__ void k_gemm_mfma(const void* __restrict__ A, const bf16* __restrict__ Wp,
                            bf16* __restrict__ C, int Nrows, const int* __restrict__ flag) {
    int warp = threadIdx.x >> 6;
    int lane = threadIdx.x & 63;
    int wr = warp >> 1;
    int wc = warp & 1;
    long rowBase = (long)blockIdx.x * 64 + wr * 32;
    int colBase = wc * 128;
    int m = lane & 31;
    int g = lane >> 5;
    long r = rowBase + m;
    if (r >= Nrows) r = Nrows - 1;
    int isf32 = ADAPT ? *flag : 0;
    const short* Ab = (const short*)A + r * 256 + g * 8;
    const float* Af = (const float*)A + r * 256 + g * 8;
    const short* Wps = (const short*)Wp;
    f32x16 acc[4] = {};
    for (int kt = 0; kt < 16; ++kt) {
        bf16x8 af;
        if (ADAPT && isf32) {
            float4 x0 = *(const float4*)(Af + kt * 16);
            float4 x1 = *(const float4*)(Af + kt * 16 + 4);
            union { bf16x8 v; short s[8]; } t;
            t.s[0] = f2b_raw(x0.x); t.s[1] = f2b_raw(x0.y);
            t.s[2] = f2b_raw(x0.z); t.s[3] = f2b_raw(x0.w);
            t.s[4] = f2b_raw(x1.x); t.s[5] = f2b_raw(x1.y);
            t.s[6] = f2b_raw(x1.z); t.s[7] = f2b_raw(x1.w);
            af = t.v;
        } else {
            af = *(const bf16x8*)(Ab + kt * 16);
        }
#pragma unroll
        for (int ct = 0; ct < 4; ++ct) {
            int nt = wc * 4 + ct;
            bf16x8 bfr = *(const bf16x8*)(Wps + (((nt << 4) + kt) << 9) + lane * 8);
            acc[ct] = __builtin_amdgcn_mfma_f32_32x32x16_bf16(af, bfr, acc[ct], 0, 0, 0);
        }
    }
#pragma unroll
    for (int ct = 0; ct < 4; ++ct) {
#pragma unroll
        for (int i = 0; i < 16; ++i) {
            long row = rowBase + (i & 3) + 8 * (i >> 2) + 4 * g;
            if (row < Nrows)
                C[row * 256 + colBase + ct * 32 + m] = __float2bfloat16(acc[ct][i]);
        }
    }
}

// C[N,64] = A[N,256](bf16) @ combined final weights (fragment-packed)
__global__ void k_gemm_mfma64(const bf16* __restrict__ A, const bf16* __restrict__ Wp,
                              bf16* __restrict__ C, int Nrows) {
    int warp = threadIdx.x >> 6;
    int lane = threadIdx.x & 63;
    long rowBase = (long)blockIdx.x * 128 + warp * 32;
    int m = lane & 31;
    int g = lane >> 5;
    long r = rowBase + m;
    if (r >= Nrows) r = Nrows - 1;
    const short* Arow = (const short*)A + r * 256 + g * 8;
    const short* Wps = (const short*)Wp;
    f32x16 acc[2] = {};
    for (int kt = 0; kt < 16; ++kt) {
        bf16x8 af = *(const bf16x8*)(Arow + kt * 16);
#pragma unroll
        for (int ct = 0; ct < 2; ++ct) {
            bf16x8 bfr = *(const bf16x8*)(Wps + (((ct << 4) + kt) << 9) + lane * 8);
            acc[ct] = __builtin_amdgcn_mfma_f32_32x32x16_bf16(af, bfr, acc[ct], 0, 0, 0);
        }
    }
#pragma unroll
    for (int ct = 0; ct < 2; ++ct) {
#pragma unroll
        for (int i = 0; i < 16; ++i) {
            long row = rowBase + (i & 3) + 8 * (i >> 2) + 4 * g;
            if (row < Nrows)
                C[row * 64 + ct * 32 + m] = __float2bfloat16(acc[ct][i]);
        }
    }
}

// ---------------- Fused GATv2 layer: 8 edges/iter (2 per slot), 16 lanes/edge ----------
__global__ void k_gat_fused(const uint4* __restrict__ f, const bf16* __restrict__ a,
                            const int* __restrict__ rowptr, const int* __restrict__ csr_src,
                            const uint4* __restrict__ res, uint4* __restrict__ out,
                            int N, int mode) {
    int n = (blockIdx.x * blockDim.x + threadIdx.x) >> 6;
    int lane = threadIdx.x & 63;
    if (n >= N) return;
    int j = lane >> 4, l = lane & 15;

    Q16 fdq, aq;
    fdq.q[0] = f[(long)n * 32 + 2 * l];
    fdq.q[1] = f[(long)n * 32 + 2 * l + 1];
    aq.q[0] = ((const uint4*)a)[2 * l];
    aq.q[1] = ((const uint4*)a)[2 * l + 1];
    f32x2 fd2[8], a6[8], a4[8];
#pragma unroll
    for (int i = 0; i < 8; ++i) {
        f32x2 fv, av;
        fv.x = __uint_as_float(fdq.u[i] << 16);
        fv.y = __uint_as_float(fdq.u[i] & 0xffff0000u);
        av.x = __uint_as_float(aq.u[i] << 16);
        av.y = __uint_as_float(aq.u[i] & 0xffff0000u);
        fd2[i] = fv;
        a6[i] = 0.6f * av;
        a4[i] = 0.4f * av;
    }

    int p0 = rowptr[n], p1 = rowptr[n + 1];
    int iters = (p1 - p0 + 3) >> 2;
    float z = 0.f;
    f32x2 acc[8] = {};

    int p = p0 + j;
    int pc = p1 - 1;
    Q16 A0, A1, B0, B1;
    {
        int s0 = csr_src[min(p, pc)];
        A0.q[0] = f[(long)s0 * 32 + 2 * l];
        A0.q[1] = f[(long)s0 * 32 + 2 * l + 1];
        int s1 = csr_src[min(p + 4, pc)];
        A1.q[0] = f[(long)s1 * 32 + 2 * l];
        A1.q[1] = f[(long)s1 * 32 + 2 * l + 1];
    }
    for (int i = 0; i < iters; i += 2) {
        int s0 = csr_src[min(p + 8, pc)];
        B0.q[0] = f[(long)s0 * 32 + 2 * l];
        B0.q[1] = f[(long)s0 * 32 + 2 * l + 1];
        int s1 = csr_src[min(p + 12, pc)];
        B1.q[0] = f[(long)s1 * 32 + 2 * l];
        B1.q[1] = f[(long)s1 * 32 + 2 * l + 1];

#pragma unroll
        for (int half = 0; half < 2; ++half) {
            if (half == 1 && i + 1 >= iters) break;
            const Q16& cur = half ? A1 : A0;
            int pp = p + half * 4;
            f32x2 fs[8];
            f32x2 t2 = {0.f, 0.f};
#pragma unroll
            for (int k = 0; k < 8; ++k) {
                f32x2 fv;
                fv.x = __uint_as_float(cur.u[k] << 16);
                fv.y = __uint_as_float(cur.u[k] & 0xffff0000u);
                fs[k] = fv;
                f32x2 u = fv + fd2[k];
                f32x2 ua;
                ua.x = __uint_as_float(__float_as_uint(u.x) & 0x7fffffffu);
                ua.y = __uint_as_float(__float_as_uint(u.y) & 0x7fffffffu);
                t2 = a6[k] * u + t2;
                t2 = a4[k] * ua + t2;
            }
            float t = t2.x + t2.y;
            t += __shfl_xor(t, 1);
            t += __shfl_xor(t, 2);
            float wgt = (pp < p1) ? __expf(t) : 0.f;
            z += wgt;
            f32x2 w2 = {wgt, wgt};
#pragma unroll
            for (int k = 0; k < 8; ++k) acc[k] = w2 * fs[k] + acc[k];
        }
        A0 = B0;
        A1 = B1;
        p += 8;
    }
    z += __shfl_xor(z, 16);
    z += __shfl_xor(z, 32);
#pragma unroll
    for (int k = 0; k < 8; ++k) {
        acc[k].x += __shfl_xor(acc[k].x, 16);
        acc[k].x += __shfl_xor(acc[k].x, 32);
        acc[k].y += __shfl_xor(acc[k].y, 16);
        acc[k].y += __shfl_xor(acc[k].y, 32);
    }
    if (j < 2) {
        float invz = 1.f / z;
        float o[8];
#pragma unroll
        for (int k = 0; k < 4; ++k) {
            int kk = j * 4 + k;
            o[2 * k]     = acc[kk].x * invz;
            o[2 * k + 1] = acc[kk].y * invz;
        }
        if (mode == 1) {
            uint4 rq = res[(long)n * 32 + 2 * l + j];
            const unsigned* ru = (const unsigned*)&rq;
#pragma unroll
            for (int k = 0; k < 4; ++k) {
                o[2 * k]     += __uint_as_float(ru[k] << 16);
                o[2 * k + 1] += __uint_as_float(ru[k] & 0xffff0000u);
            }
        }
        union { uint4 q; short s[8]; } ob;
#pragma unroll
        for (int k = 0; k < 8; ++k) {
            float v = o[k] > 0.f ? o[k] : (__expf(o[k]) - 1.f);
            ob.s[k] = f2b_raw(v);
        }
        out[(long)n * 32 + 2 * l + j] = ob.q;
    }
}

// ---------------- Fused final layer: 4 edge slots x 16 lanes, 2 dims/lane ----------
// fr2 row = 64 bf16 = 32 uints: [0..15] = f2 (32 dims), [16..31] = r2.
__global__ void k_gat_fused_fin(const unsigned* __restrict__ fr2u, const bf16* __restrict__ a2,
                                const int* __restrict__ rowptr, const int* __restrict__ csr_src,
                                void* __restrict__ outraw, int N, const int* __restrict__ flag) {
    int n = (blockIdx.x * blockDim.x + threadIdx.x) >> 6;
    int lane = threadIdx.x & 63;
    if (n >= N) return;
    int j = lane >> 4, l = lane & 15;

    unsigned fdu = fr2u[(long)n * 32 + l];
    unsigned au  = ((const unsigned*)a2)[l];
    f32x2 fd2, a6, a4;
    fd2.x = __uint_as_float(fdu << 16);
    fd2.y = __uint_as_float(fdu & 0xffff0000u);
    float ax = __uint_as_float(au << 16);
    float ay = __uint_as_float(au & 0xffff0000u);
    a6.x = 0.6f * ax; a6.y = 0.6f * ay;
    a4.x = 0.4f * ax; a4.y = 0.4f * ay;

    int p0 = rowptr[n], p1 = rowptr[n + 1];
    int iters = (p1 - p0 + 3) >> 2;
    float z = 0.f;
    f32x2 acc = {0.f, 0.f};

    int p = p0 + j;
    int pc = p1 - 1;
    unsigned A0, A1, B0, B1;
    A0 = fr2u[(long)csr_src[min(p, pc)] * 32 + l];
    A1 = fr2u[(long)csr_src[min(p + 4, pc)] * 32 + l];
    for (int i = 0; i < iters; i += 2) {
        B0 = fr2u[(long)csr_src[min(p + 8, pc)] * 32 + l];
        B1 = fr2u[(long)csr_src[min(p + 12, pc)] * 32 + l];
#pragma unroll
        for (int half = 0; half < 2; ++half) {
            if (half == 1 && i + 1 >= iters) break;
            unsigned cu = half ? A1 : A0;
            int pp = p + half * 4;
            f32x2 fs;
            fs.x = __uint_as_float(cu << 16);
            fs.y = __uint_as_float(cu & 0xffff0000u);
            f32x2 u = fs + fd2;
            f32x2 ua;
            ua.x = __uint_as_float(__float_as_uint(u.x) & 0x7fffffffu);
            ua.y = __uint_as_float(__float_as_uint(u.y) & 0x7fffffffu);
            f32x2 t2 = a6 * u + a4 * ua;
            float t = t2.x + t2.y;
            t += __shfl_xor(t, 1);
            t += __shfl_xor(t, 2);
            t += __shfl_xor(t, 4);
            t += __shfl_xor(t, 8);
            float wgt = (pp < p1) ? __expf(t) : 0.f;
            z += wgt;
            f32x2 w2 = {wgt, wgt};
            acc = w2 * fs + acc;
        }
        A0 = B0;
        A1 = B1;
        p += 8;
    }
    z += __shfl_xor(z, 16);
    z += __shfl_xor(z, 32);
    acc.x += __shfl_xor(acc.x, 16);
    acc.x += __shfl_xor(acc.x, 32);
    acc.y += __shfl_xor(acc.y, 16);
    acc.y += __shfl_xor(acc.y, 32);
    if (j == 0) {
        unsigned ru = fr2u[(long)n * 32 + 16 + l];
        float invz = 1.f / z;
        float o0 = acc.x * invz + __uint_as_float(ru << 16);
        float o1 = acc.y * invz + __uint_as_float(ru & 0xffff0000u);
        if (*flag) {
            float2 ov = {o0, o1};
            ((float2*)outraw)[(long)n * 16 + l] = ov;
        } else {
            unsigned ob = ((unsigned)(unsigned short)f2b_raw(o0)) |
                          (((unsigned)(unsigned short)f2b_raw(o1)) << 16);
            ((unsigned*)outraw)[(long)n * 16 + l] = ob;
        }
    }
}

extern "C" void kernel_launch(void* const* d_in, const int* in_sizes, int n_in,
                              void* d_out, int out_size, void* d_ws, size_t ws_size,
                              hipStream_t stream) {
    const int N = in_sizes[0] / 256;
    const int E = in_sizes[1];

    const void* x   = d_in[0];
    const int*  src = (const int*)d_in[1];
    const int*  dst = (const int*)d_in[2];

    // ---- workspace carve ----
    char* w = (char*)d_ws;
    auto alloc = [&](size_t bytes) -> char* {
        char* p = w;
        w += (bytes + 15) & ~(size_t)15;
        return p;
    };
    bf16* buf0 = (bf16*)alloc((size_t)N * 256 * 2);  // hB
    bf16* buf1 = (bf16*)alloc((size_t)N * 256 * 2);  // hA
    bf16* buf2 = (bf16*)alloc((size_t)N * 256 * 2);  // fB / fr2
    int* csr_src = (int*)alloc((size_t)E * 4);
    int* rowptr  = (int*)alloc((size_t)(N + 1) * 4);
    int* cursor  = (int*)alloc((size_t)N * 4);
    int* cnt     = (int*)alloc((size_t)N * 4);
    int* bsum    = (int*)alloc((size_t)1024 * 4);
    bf16* W0p  = (bf16*)alloc((size_t)65536 * 2);
    bf16* W1p  = (bf16*)alloc((size_t)65536 * 2);
    bf16* W2fp = (bf16*)alloc((size_t)64 * 256 * 2);
    bf16* a0c  = (bf16*)alloc((size_t)256 * 2);
    bf16* a1c  = (bf16*)alloc((size_t)256 * 2);
    bf16* a2c  = (bf16*)alloc((size_t)32 * 2);
    int*  flag = (int*)alloc(16);

    bf16* hA  = buf1;
    bf16* fB  = buf2;
    bf16* hB  = buf0;
    bf16* fr2 = buf2;

    // ---- dtype detect + cnt zero (one kernel) + merged weight prep ----
    k_detect<<<(N + 255) / 256, 256, 0, stream>>>(x, flag, cnt, N);
    k_prep<<<(147456 + 544 + 255) / 256, 256, 0, stream>>>(
        d_in[3], d_in[5], d_in[7], d_in[9], d_in[4], d_in[6], d_in[8],
        W0p, W1p, W2fp, a0c, a1c, a2c, flag);

    // ---- CSR build ----
    const int B = (N + 1023) / 1024;
    k_hist<<<(E + 255) / 256, 256, 0, stream>>>(dst, cnt, E);
    k_bsum<<<B, 256, 0, stream>>>(cnt, bsum, N);
    k_bscan<<<1, 1024, 0, stream>>>(bsum, B);
    k_scanwrite<<<B, 256, 0, stream>>>(cnt, bsum, rowptr, cursor, N, E);
    k_scatter<<<(E + 255) / 256, 256, 0, stream>>>(src, dst, cursor, csr_src, E);

    const int ngrid4 = (int)(((long)N * 64 + 255) / 256);

    // ---- layer 0 (x read directly, fp32 converted in-flight) ----
    k_gemm_mfma<1><<<(N + 63) / 64, 256, 0, stream>>>(x, W0p, fB, N, flag);
    k_gat_fused<<<ngrid4, 256, 0, stream>>>((const uint4*)fB, a0c, rowptr, csr_src,
                                            nullptr, (uint4*)hA, N, 0);
    // ---- layer 1 (hA is ALWAYS bf16 -> non-adaptive) ----
    k_gemm_mfma<0><<<(N + 63) / 64, 256, 0, stream>>>(hA, W1p, fB, N, flag);
    k_gat_fused<<<ngrid4, 256, 0, stream>>>((const uint4*)fB, a1c, rowptr, csr_src,
                                            (const uint4*)hA, (uint4*)hB, N, 1);
    // ---- final layer ----
    k_gemm_mfma64<<<(N + 127) / 128, 256, 0, stream>>>(hB, W2fp, fr2, N);
    k_gat_fused_fin<<<ngrid4, 256, 0, stream>>>((const unsigned*)fr2, a2c, rowptr, csr_src,
                                                d_out, N, flag);
}